// Round 8
// baseline (1459.850 us; speedup 1.0000x reference)
//
#include <hip/hip_runtime.h>
#include <math.h>

#define BB 8
#define CC 32
#define TT 9
#define LL 512
#define HH 8
#define DD 4
#define NBT (BB*TT)          // 72
#define RELN (2*LL-1)        // 1023
#define RLN2 1.4426950408889634f

typedef float v2f __attribute__((ext_vector_type(2)));

// ---- mixed bias, reversed + log2e-prescaled: mbr[Ho][x] = log2e * sum_h rpb[h][1022-x] Wl[h][Ho]
// (consumer index: x = j - i + 511  <=>  rel idx i - j + 511 = 1022 - x)
__global__ void mixed_bias_kernel(const float* __restrict__ rpb,
                                  const float* __restrict__ Wl,
                                  float* __restrict__ mbr) {
  int x = blockIdx.x * blockDim.x + threadIdx.x;
  if (x >= RELN) return;
  int idx = 1022 - x;
  float r[HH];
  #pragma unroll
  for (int h = 0; h < HH; ++h) r[h] = rpb[h*RELN + idx];
  #pragma unroll
  for (int Ho = 0; Ho < HH; ++Ho) {
    float acc = 0.f;
    #pragma unroll
    for (int h = 0; h < HH; ++h) acc += r[h] * Wl[h*HH + Ho];
    mbr[Ho*1024 + x] = RLN2 * acc;
  }
}

// ---------------- transpose pl_w (512x512): outT[l][l'] = in[l'][l] ----------------
__global__ __launch_bounds__(256) void transpose512_kernel(const float* __restrict__ in,
                                                           float* __restrict__ outT) {
  __shared__ float tile[32][33];
  int bx = blockIdx.x * 32, by = blockIdx.y * 32;
  int tx = threadIdx.x & 31, ty = threadIdx.x >> 5;   // 32x8
  #pragma unroll
  for (int yy = ty; yy < 32; yy += 8)
    tile[yy][tx] = in[(by + yy)*LL + bx + tx];
  __syncthreads();
  #pragma unroll
  for (int yy = ty; yy < 32; yy += 8)
    outT[(bx + yy)*LL + by + tx] = tile[tx][yy];
}

// ---------------- q/k/v projection + l2norm ----------------
// q,k,v all [bt][h][l][d]; q scaled by 0.5*log2e (1/sqrt(D) + exp2 prescale folded in)
__global__ __launch_bounds__(256) void proj_kernel(
    const float* __restrict__ x,
    const float* __restrict__ Wq, const float* __restrict__ bq,
    const float* __restrict__ Wk, const float* __restrict__ bk,
    const float* __restrict__ Wv, const float* __restrict__ bv,
    float* __restrict__ qo, float* __restrict__ ko, float* __restrict__ vo) {
  int g = blockIdx.x * 256 + threadIdx.x;    // 0..36863
  int l  = g & (LL-1);
  int bt = g >> 9;
  int b = bt / TT, t = bt - b*TT;

  float xv[CC];
  #pragma unroll
  for (int c = 0; c < CC; ++c)
    xv[c] = x[((b*CC + c)*TT + t)*LL + l];

  const float* Ws[3] = {Wq, Wk, Wv};
  const float* bs[3] = {bq, bk, bv};
  float* ds[3] = {qo, ko, vo};
  #pragma unroll
  for (int p = 0; p < 3; ++p) {
    const float* W = Ws[p];
    const float* bi = bs[p];
    float* dst = ds[p];
    const float post = (p == 0) ? 0.5f * RLN2 : 1.0f;
    #pragma unroll
    for (int h = 0; h < HH; ++h) {
      float yv[DD];
      #pragma unroll
      for (int d = 0; d < DD; ++d) {
        int co = h*DD + d;
        float acc = bi[co];
        #pragma unroll
        for (int ci = 0; ci < CC; ++ci) acc += xv[ci] * W[co*CC + ci];
        yv[d] = acc;
      }
      float n = sqrtf(yv[0]*yv[0] + yv[1]*yv[1] + yv[2]*yv[2] + yv[3]*yv[3]);
      float inv = post / fmaxf(n, 1e-12f);
      float4 o4 = make_float4(yv[0]*inv, yv[1]*inv, yv[2]*inv, yv[3]*inv);
      *reinterpret_cast<float4*>(&dst[((size_t)(bt*HH + h))*(LL*DD) + l*DD]) = o4;
    }
  }
}

// ---------------- fused attention (v7: 128-thr pair blocks, one-pass, no K LDS) ----------
// 4608 blocks x 128 thr (2 waves = 1 pair). Pair owns 8 rows serially; per row,
// wave-half owns 256 j, each lane 4 j (lg2[8][2] v2f). K,V from L2 ([h][j][d],
// coalesced, XCD-chunked so one bt's K+V stays on one XCD). Barriers sync 2 waves.
#define ACC(e) acc2[(e)>>1][(e)&1]
__global__ __launch_bounds__(128, 4) void attn_kernel(
    const float* __restrict__ q, const float* __restrict__ k, const float* __restrict__ v,
    const float* __restrict__ Wl, const float* __restrict__ Wc,
    const float* __restrict__ mbr, float* __restrict__ xatt) {
  __shared__ float sS[2][HH];       // per-wave softmax partial sums
  __shared__ float opart[2][CC];    // per-wave PV partials

  // XCD swizzle: 4608 blocks, 576 per XCD (bijective); blocks of one bt adjacent
  const int wgid = blockIdx.x;
  const int id   = (wgid & 7) * 576 + (wgid >> 3);
  const int bt   = id >> 6;     // [0,72)
  const int rg   = id & 63;     // row-group of 8 rows

  const int tid  = threadIdx.x;
  const int half = __builtin_amdgcn_readfirstlane(tid >> 6);   // 0,1
  const int lane = tid & 63;
  const int jbase = half*256 + lane;    // j = jbase + {0,64,128,192}

  const float* kb = k + (size_t)bt*(HH*LL*DD);
  const float* vb = v + (size_t)bt*(HH*LL*DD);

  #pragma unroll 1
  for (int r = 0; r < 8; ++r) {
    const int i = rg*8 + r;

    // ---- q row (uniform address -> broadcast loads)
    float4 qv[HH];
    {
      const float* qrow = q + (size_t)(bt*HH)*(LL*DD) + i*DD;
      #pragma unroll
      for (int h = 0; h < HH; ++h)
        qv[h] = *reinterpret_cast<const float4*>(&qrow[h*(LL*DD)]);
    }

    // ---- init logits with mixed rel-pos bias (coalesced scalar loads)
    v2f lg2[HH][2];
    {
      const int ob = jbase - i + 511;
      #pragma unroll
      for (int H = 0; H < HH; ++H) {
        const float* m = &mbr[H*1024 + ob];
        lg2[H][0] = (v2f){ m[0],   m[64]  };
        lg2[H][1] = (v2f){ m[128], m[192] };
      }
    }

    // ---- scores + head-mix 1 (one pass; K from L2, coalesced)
    #pragma unroll
    for (int p = 0; p < 2; ++p) {
      const int j0 = jbase + p*128;
      v2f s2[HH];
      #pragma unroll
      for (int h = 0; h < HH; ++h) {
        float4 a = *reinterpret_cast<const float4*>(&kb[(h*LL + j0)*DD]);
        float4 c = *reinterpret_cast<const float4*>(&kb[(h*LL + j0 + 64)*DD]);
        s2[h][0] = qv[h].x*a.x + qv[h].y*a.y + qv[h].z*a.z + qv[h].w*a.w;
        s2[h][1] = qv[h].x*c.x + qv[h].y*c.y + qv[h].z*c.z + qv[h].w*c.w;
      }
      #pragma unroll
      for (int h = 0; h < HH; ++h) {
        #pragma unroll
        for (int H = 0; H < HH; ++H) {
          float w = Wl[h*HH + H];
          lg2[H][p] += s2[h] * (v2f){w, w};
        }
      }
    }

    // ---- exp + wave butterfly sum per head
    float Sown[HH];
    #pragma unroll
    for (int H = 0; H < HH; ++H) {
      v2f e0 = (v2f){ exp2f(lg2[H][0][0]), exp2f(lg2[H][0][1]) };
      v2f e1 = (v2f){ exp2f(lg2[H][1][0]), exp2f(lg2[H][1][1]) };
      lg2[H][0] = e0; lg2[H][1] = e1;
      float t = (e0[0] + e0[1]) + (e1[0] + e1[1]);
      #pragma unroll
      for (int off = 32; off >= 1; off >>= 1) t += __shfl_xor(t, off);
      Sown[H] = t;
    }
    if (lane == 0) {
      *reinterpret_cast<float4*>(&sS[half][0]) = make_float4(Sown[0], Sown[1], Sown[2], Sown[3]);
      *reinterpret_cast<float4*>(&sS[half][4]) = make_float4(Sown[4], Sown[5], Sown[6], Sown[7]);
    }
    __syncthreads();
    {
      const int pw = half ^ 1;
      #pragma unroll
      for (int H = 0; H < HH; ++H) {
        float inv = __builtin_amdgcn_rcpf(Sown[H] + sS[pw][H]);
        lg2[H][0] *= (v2f){inv, inv};
        lg2[H][1] *= (v2f){inv, inv};
      }
    }

    // ---- head-mix 2 + PV (V from L2, coalesced)
    v2f acc2[16];
    #pragma unroll
    for (int e = 0; e < 16; ++e) acc2[e] = (v2f){0.f, 0.f};
    #pragma unroll
    for (int p = 0; p < 2; ++p) {
      const int j0 = jbase + p*128;
      #pragma unroll
      for (int Hp = 0; Hp < HH; ++Hp) {
        v2f a2;
        {
          float w = Wc[Hp];
          a2 = lg2[0][p] * (v2f){w, w};
        }
        #pragma unroll
        for (int H = 1; H < HH; ++H) {
          float w = Wc[H*HH + Hp];
          a2 += lg2[H][p] * (v2f){w, w};
        }
        float4 va = *reinterpret_cast<const float4*>(&vb[(Hp*LL + j0)*DD]);
        float4 vc = *reinterpret_cast<const float4*>(&vb[(Hp*LL + j0 + 64)*DD]);
        acc2[Hp*2+0] += (v2f){a2[0], a2[0]} * (v2f){va.x, va.y}
                      + (v2f){a2[1], a2[1]} * (v2f){vc.x, vc.y};
        acc2[Hp*2+1] += (v2f){a2[0], a2[0]} * (v2f){va.z, va.w}
                      + (v2f){a2[1], a2[1]} * (v2f){vc.z, vc.w};
      }
    }

    // ---- fold reduction: 32 values over 64 lanes (exchange-and-halve)
    #pragma unroll
    for (int t = 0; t < 16; ++t) {
      float send = (lane & 1) ? ACC(t) : ACC(16 + t);
      float recv = __shfl_xor(send, 1);
      float keep = (lane & 1) ? ACC(16 + t) : ACC(t);
      ACC(t) = keep + recv;
    }
    #pragma unroll
    for (int t = 0; t < 8; ++t) {
      float send = (lane & 2) ? ACC(t) : ACC(8 + t);
      float recv = __shfl_xor(send, 2);
      float keep = (lane & 2) ? ACC(8 + t) : ACC(t);
      ACC(t) = keep + recv;
    }
    #pragma unroll
    for (int t = 0; t < 4; ++t) {
      float send = (lane & 4) ? ACC(t) : ACC(4 + t);
      float recv = __shfl_xor(send, 4);
      float keep = (lane & 4) ? ACC(4 + t) : ACC(t);
      ACC(t) = keep + recv;
    }
    #pragma unroll
    for (int t = 0; t < 2; ++t) {
      float send = (lane & 8) ? ACC(t) : ACC(2 + t);
      float recv = __shfl_xor(send, 8);
      float keep = (lane & 8) ? ACC(2 + t) : ACC(t);
      ACC(t) = keep + recv;
    }
    {
      float send = (lane & 16) ? ACC(0) : ACC(1);
      float recv = __shfl_xor(send, 16);
      float keep = (lane & 16) ? ACC(1) : ACC(0);
      ACC(0) = keep + recv;
    }
    ACC(0) += __shfl_xor(ACC(0), 32);
    if (lane < 32) {
      int e = ((lane & 1) << 4) | ((lane & 2) << 2) | (lane & 4) |
              ((lane & 8) >> 2) | ((lane & 16) >> 4);
      opart[half][e] = ACC(0);
    }
    __syncthreads();
    if (tid < 32)
      xatt[((size_t)bt*LL + i)*CC + tid] = opart[0][tid] + opart[1][tid];
  }
}

// ---------------- Wm projection (4-way co-split); t<8 -> out, t==8 -> xm8 ----------------
// block (64,4): x = l-chunk lane, y = co-quarter. 576 blocks.
__global__ __launch_bounds__(256) void wm_kernel(
    const float* __restrict__ xatt, const float* __restrict__ Wm, const float* __restrict__ bm,
    float* __restrict__ out, float* __restrict__ xm8) {
  int gl = blockIdx.x * 64 + threadIdx.x;   // 0..36863
  int qy = threadIdx.y;                     // 0..3
  int l  = gl & (LL-1);
  int bt = gl >> 9;
  int b = bt / TT, t = bt - b*TT;
  float xv[CC];
  #pragma unroll
  for (int c = 0; c < CC; c += 4) {
    float4 x4 = *reinterpret_cast<const float4*>(&xatt[(size_t)gl*CC + c]);
    xv[c] = x4.x; xv[c+1] = x4.y; xv[c+2] = x4.z; xv[c+3] = x4.w;
  }
  #pragma unroll
  for (int u = 0; u < 8; ++u) {
    int co = qy*8 + u;
    float acc = bm[co];
    #pragma unroll
    for (int ci = 0; ci < CC; ++ci) acc += xv[ci] * Wm[co*CC + ci];
    if (t < TT-1) out[((b*CC + co)*TT + t)*LL + l] = acc;
    else          xm8[(b*CC + co)*LL + l] = acc;
  }
}

// ---------------- conv over (ci,t) + BN(eval) + ReLU ----------------
__global__ __launch_bounds__(512) void conv_kernel(
    const float* __restrict__ out, const float* __restrict__ pp,
    const float* __restrict__ cw, const float* __restrict__ cb,
    const float* __restrict__ bng, const float* __restrict__ bnb,
    float* __restrict__ yws) {
  int bc = blockIdx.x;            // b*32 + co
  int b = bc >> 5, co = bc & 31;
  int l = threadIdx.x;
  float acc = cb[co];
  #pragma unroll
  for (int ci = 0; ci < CC; ++ci) {
    const float* base = out + ((b*CC + ci)*TT)*LL + l;
    const float* w = cw + (co*CC + ci)*TT;
    #pragma unroll
    for (int t = 0; t < TT-1; ++t) acc += base[t*LL] * w[t];
    acc += pp[ci*LL + l] * w[TT-1];
  }
  float scale = bng[co] * 0.999995000037499687f;   // 1/sqrt(1+1e-5)
  float val = acc * scale + bnb[co];
  yws[bc*LL + l] = fmaxf(val, 0.f);
}

// ---------------- token-linear p = y @ pl_w.T + pl_b; out[t=8] = xm8 - p ----------------
__global__ __launch_bounds__(512) void pl_kernel(
    const float* __restrict__ yws, const float* __restrict__ plwT,
    const float* __restrict__ plb, const float* __restrict__ xm8,
    float* __restrict__ out) {
  __shared__ float sy[2][LL];
  int bc0 = blockIdx.x * 2;
  int tid = threadIdx.x;
  sy[0][tid] = yws[bc0*LL + tid];
  sy[1][tid] = yws[(bc0+1)*LL + tid];
  __syncthreads();
  float acc0 = plb[tid], acc1 = plb[tid];
  #pragma unroll 4
  for (int l = 0; l < LL; ++l) {
    float w = plwT[l*LL + tid];
    acc0 += sy[0][l] * w;
    acc1 += sy[1][l] * w;
  }
  out[(bc0*TT + (TT-1))*LL + tid]       = xm8[bc0*LL + tid] - acc0;
  out[((bc0+1)*TT + (TT-1))*LL + tid]   = xm8[(bc0+1)*LL + tid] - acc1;
}

extern "C" void kernel_launch(void* const* d_in, const int* in_sizes, int n_in,
                              void* d_out, int out_size, void* d_ws, size_t ws_size,
                              hipStream_t stream) {
  const float* x    = (const float*)d_in[0];
  const float* Wq   = (const float*)d_in[1];
  const float* bq   = (const float*)d_in[2];
  const float* Wk   = (const float*)d_in[3];
  const float* bk   = (const float*)d_in[4];
  const float* Wv   = (const float*)d_in[5];
  const float* bv   = (const float*)d_in[6];
  const float* Wm   = (const float*)d_in[7];
  const float* bm   = (const float*)d_in[8];
  const float* Wl   = (const float*)d_in[9];
  const float* Wc   = (const float*)d_in[10];
  const float* rpb  = (const float*)d_in[11];
  const float* pp   = (const float*)d_in[12];
  const float* cw   = (const float*)d_in[13];
  const float* cb   = (const float*)d_in[14];
  const float* bng  = (const float*)d_in[15];
  const float* bnb  = (const float*)d_in[16];
  const float* plw  = (const float*)d_in[17];
  const float* plb  = (const float*)d_in[18];
  float* out = (float*)d_out;

  float* ws = (float*)d_ws;
  const size_t QKV = (size_t)NBT*HH*LL*DD;     // 1179648
  float* q_ws   = ws;                 // QKV ([bt][h][l][d])
  float* k_ws   = q_ws + QKV;         // QKV ([bt][h][l][d])
  float* v_ws   = k_ws + QKV;         // QKV ([bt][h][l][d])
  float* xatt   = v_ws + QKV;         // NBT*LL*CC = 1179648
  float* xm8    = xatt + QKV;         // BB*CC*LL = 131072
  float* yws    = xm8 + (size_t)BB*CC*LL;      // 131072
  float* plwT   = yws + (size_t)BB*CC*LL;      // 262144
  float* mbias  = plwT + (size_t)LL*LL;        // 8*1024 reversed, log2e-scaled

  mixed_bias_kernel<<<2, 512, 0, stream>>>(rpb, Wl, mbias);
  transpose512_kernel<<<dim3(16,16), 256, 0, stream>>>(plw, plwT);
  proj_kernel<<<(BB*TT*LL)/256, 256, 0, stream>>>(x, Wq, bq, Wk, bk, Wv, bv, q_ws, k_ws, v_ws);
  attn_kernel<<<NBT*64, 128, 0, stream>>>(q_ws, k_ws, v_ws, Wl, Wc, mbias, xatt);
  wm_kernel<<<576, dim3(64,4), 0, stream>>>(xatt, Wm, bm, out, xm8);
  conv_kernel<<<BB*CC, LL, 0, stream>>>(out, pp, cw, cb, bng, bnb, yws);
  pl_kernel<<<(BB*CC)/2, LL, 0, stream>>>(yws, plwT, plb, xm8, out);
}

// Round 9
// 781.726 us; speedup vs baseline: 1.8675x; 1.8675x over previous
//
#include <hip/hip_runtime.h>
#include <math.h>

#define BB 8
#define CC 32
#define TT 9
#define LL 512
#define HH 8
#define DD 4
#define NBT (BB*TT)          // 72
#define RELN (2*LL-1)        // 1023
#define RLN2 1.4426950408889634f

typedef float v2f __attribute__((ext_vector_type(2)));

// ---- mixed bias, reversed + log2e-prescaled: mbr[Ho][x] = log2e * sum_h rpb[h][1022-x] Wl[h][Ho]
// (consumer index: x = j - i + 511  <=>  rel idx i - j + 511 = 1022 - x)
__global__ void mixed_bias_kernel(const float* __restrict__ rpb,
                                  const float* __restrict__ Wl,
                                  float* __restrict__ mbr) {
  int x = blockIdx.x * blockDim.x + threadIdx.x;
  if (x >= RELN) return;
  int idx = 1022 - x;
  float r[HH];
  #pragma unroll
  for (int h = 0; h < HH; ++h) r[h] = rpb[h*RELN + idx];
  #pragma unroll
  for (int Ho = 0; Ho < HH; ++Ho) {
    float acc = 0.f;
    #pragma unroll
    for (int h = 0; h < HH; ++h) acc += r[h] * Wl[h*HH + Ho];
    mbr[Ho*1024 + x] = RLN2 * acc;
  }
}

// ---------------- transpose pl_w (512x512): outT[l][l'] = in[l'][l] ----------------
__global__ __launch_bounds__(256) void transpose512_kernel(const float* __restrict__ in,
                                                           float* __restrict__ outT) {
  __shared__ float tile[32][33];
  int bx = blockIdx.x * 32, by = blockIdx.y * 32;
  int tx = threadIdx.x & 31, ty = threadIdx.x >> 5;   // 32x8
  #pragma unroll
  for (int yy = ty; yy < 32; yy += 8)
    tile[yy][tx] = in[(by + yy)*LL + bx + tx];
  __syncthreads();
  #pragma unroll
  for (int yy = ty; yy < 32; yy += 8)
    outT[(bx + yy)*LL + by + tx] = tile[tx][yy];
}

// ---------------- q/k/v projection + l2norm ----------------
// q,k,v all [bt][h][l][d]; q scaled by 0.5*log2e (1/sqrt(D) + exp2 prescale folded in)
__global__ __launch_bounds__(256) void proj_kernel(
    const float* __restrict__ x,
    const float* __restrict__ Wq, const float* __restrict__ bq,
    const float* __restrict__ Wk, const float* __restrict__ bk,
    const float* __restrict__ Wv, const float* __restrict__ bv,
    float* __restrict__ qo, float* __restrict__ ko, float* __restrict__ vo) {
  int g = blockIdx.x * 256 + threadIdx.x;    // 0..36863
  int l  = g & (LL-1);
  int bt = g >> 9;
  int b = bt / TT, t = bt - b*TT;

  float xv[CC];
  #pragma unroll
  for (int c = 0; c < CC; ++c)
    xv[c] = x[((b*CC + c)*TT + t)*LL + l];

  const float* Ws[3] = {Wq, Wk, Wv};
  const float* bs[3] = {bq, bk, bv};
  float* ds[3] = {qo, ko, vo};
  #pragma unroll
  for (int p = 0; p < 3; ++p) {
    const float* W = Ws[p];
    const float* bi = bs[p];
    float* dst = ds[p];
    const float post = (p == 0) ? 0.5f * RLN2 : 1.0f;
    #pragma unroll
    for (int h = 0; h < HH; ++h) {
      float yv[DD];
      #pragma unroll
      for (int d = 0; d < DD; ++d) {
        int co = h*DD + d;
        float acc = bi[co];
        #pragma unroll
        for (int ci = 0; ci < CC; ++ci) acc += xv[ci] * W[co*CC + ci];
        yv[d] = acc;
      }
      float n = sqrtf(yv[0]*yv[0] + yv[1]*yv[1] + yv[2]*yv[2] + yv[3]*yv[3]);
      float inv = post / fmaxf(n, 1e-12f);
      float4 o4 = make_float4(yv[0]*inv, yv[1]*inv, yv[2]*inv, yv[3]*inv);
      *reinterpret_cast<float4*>(&dst[((size_t)(bt*HH + h))*(LL*DD) + l*DD]) = o4;
    }
  }
}

// ---------------- fused attention (v8: v7 pair blocks, VGPR cap fixed) ----------
// 4608 blocks x 128 thr (2 waves = 1 pair). Pair owns 8 rows serially; per row,
// wave-half owns 256 j, each lane 4 j (lg2[8][2] v2f). K,V from L2 ([h][j][d],
// coalesced, XCD-chunked so one bt's K+V stays on one XCD). Barriers sync 2 waves.
// launch_bounds(128,2): VGPR cap 256 -> allocator lands ~120, NO spill.
// (NEVER declare >2 waves/EU here: live state ~110-120 regs; 64-cap spilled 3.6 GB.)
#define ACC(e) acc2[(e)>>1][(e)&1]
__global__ __launch_bounds__(128, 2) void attn_kernel(
    const float* __restrict__ q, const float* __restrict__ k, const float* __restrict__ v,
    const float* __restrict__ Wl, const float* __restrict__ Wc,
    const float* __restrict__ mbr, float* __restrict__ xatt) {
  __shared__ float sS[2][HH];       // per-wave softmax partial sums
  __shared__ float opart[2][CC];    // per-wave PV partials

  // XCD swizzle: 4608 blocks, 576 per XCD (bijective); blocks of one bt adjacent
  const int wgid = blockIdx.x;
  const int id   = (wgid & 7) * 576 + (wgid >> 3);
  const int bt   = id >> 6;     // [0,72)
  const int rg   = id & 63;     // row-group of 8 rows

  const int tid  = threadIdx.x;
  const int half = __builtin_amdgcn_readfirstlane(tid >> 6);   // 0,1
  const int lane = tid & 63;
  const int jbase = half*256 + lane;    // j = jbase + {0,64,128,192}

  const float* kb = k + (size_t)bt*(HH*LL*DD);
  const float* vb = v + (size_t)bt*(HH*LL*DD);

  #pragma unroll 1
  for (int r = 0; r < 8; ++r) {
    const int i = rg*8 + r;

    // ---- q row (uniform address -> broadcast loads)
    float4 qv[HH];
    {
      const float* qrow = q + (size_t)(bt*HH)*(LL*DD) + i*DD;
      #pragma unroll
      for (int h = 0; h < HH; ++h)
        qv[h] = *reinterpret_cast<const float4*>(&qrow[h*(LL*DD)]);
    }

    // ---- init logits with mixed rel-pos bias (coalesced scalar loads)
    v2f lg2[HH][2];
    {
      const int ob = jbase - i + 511;
      #pragma unroll
      for (int H = 0; H < HH; ++H) {
        const float* m = &mbr[H*1024 + ob];
        lg2[H][0] = (v2f){ m[0],   m[64]  };
        lg2[H][1] = (v2f){ m[128], m[192] };
      }
    }

    // ---- scores + head-mix 1 (one pass; K from L2, coalesced)
    #pragma unroll
    for (int p = 0; p < 2; ++p) {
      const int j0 = jbase + p*128;
      v2f s2[HH];
      #pragma unroll
      for (int h = 0; h < HH; ++h) {
        float4 a = *reinterpret_cast<const float4*>(&kb[(h*LL + j0)*DD]);
        float4 c = *reinterpret_cast<const float4*>(&kb[(h*LL + j0 + 64)*DD]);
        s2[h][0] = qv[h].x*a.x + qv[h].y*a.y + qv[h].z*a.z + qv[h].w*a.w;
        s2[h][1] = qv[h].x*c.x + qv[h].y*c.y + qv[h].z*c.z + qv[h].w*c.w;
      }
      #pragma unroll
      for (int h = 0; h < HH; ++h) {
        #pragma unroll
        for (int H = 0; H < HH; ++H) {
          float w = Wl[h*HH + H];
          lg2[H][p] += s2[h] * (v2f){w, w};
        }
      }
    }

    // ---- exp + wave butterfly sum per head
    float Sown[HH];
    #pragma unroll
    for (int H = 0; H < HH; ++H) {
      v2f e0 = (v2f){ exp2f(lg2[H][0][0]), exp2f(lg2[H][0][1]) };
      v2f e1 = (v2f){ exp2f(lg2[H][1][0]), exp2f(lg2[H][1][1]) };
      lg2[H][0] = e0; lg2[H][1] = e1;
      float t = (e0[0] + e0[1]) + (e1[0] + e1[1]);
      #pragma unroll
      for (int off = 32; off >= 1; off >>= 1) t += __shfl_xor(t, off);
      Sown[H] = t;
    }
    if (lane == 0) {
      *reinterpret_cast<float4*>(&sS[half][0]) = make_float4(Sown[0], Sown[1], Sown[2], Sown[3]);
      *reinterpret_cast<float4*>(&sS[half][4]) = make_float4(Sown[4], Sown[5], Sown[6], Sown[7]);
    }
    __syncthreads();
    {
      const int pw = half ^ 1;
      #pragma unroll
      for (int H = 0; H < HH; ++H) {
        float inv = __builtin_amdgcn_rcpf(Sown[H] + sS[pw][H]);
        lg2[H][0] *= (v2f){inv, inv};
        lg2[H][1] *= (v2f){inv, inv};
      }
    }

    // ---- head-mix 2 + PV (V from L2, coalesced)
    v2f acc2[16];
    #pragma unroll
    for (int e = 0; e < 16; ++e) acc2[e] = (v2f){0.f, 0.f};
    #pragma unroll
    for (int p = 0; p < 2; ++p) {
      const int j0 = jbase + p*128;
      #pragma unroll
      for (int Hp = 0; Hp < HH; ++Hp) {
        v2f a2;
        {
          float w = Wc[Hp];
          a2 = lg2[0][p] * (v2f){w, w};
        }
        #pragma unroll
        for (int H = 1; H < HH; ++H) {
          float w = Wc[H*HH + Hp];
          a2 += lg2[H][p] * (v2f){w, w};
        }
        float4 va = *reinterpret_cast<const float4*>(&vb[(Hp*LL + j0)*DD]);
        float4 vc = *reinterpret_cast<const float4*>(&vb[(Hp*LL + j0 + 64)*DD]);
        acc2[Hp*2+0] += (v2f){a2[0], a2[0]} * (v2f){va.x, va.y}
                      + (v2f){a2[1], a2[1]} * (v2f){vc.x, vc.y};
        acc2[Hp*2+1] += (v2f){a2[0], a2[0]} * (v2f){va.z, va.w}
                      + (v2f){a2[1], a2[1]} * (v2f){vc.z, vc.w};
      }
    }

    // ---- fold reduction: 32 values over 64 lanes (exchange-and-halve)
    #pragma unroll
    for (int t = 0; t < 16; ++t) {
      float send = (lane & 1) ? ACC(t) : ACC(16 + t);
      float recv = __shfl_xor(send, 1);
      float keep = (lane & 1) ? ACC(16 + t) : ACC(t);
      ACC(t) = keep + recv;
    }
    #pragma unroll
    for (int t = 0; t < 8; ++t) {
      float send = (lane & 2) ? ACC(t) : ACC(8 + t);
      float recv = __shfl_xor(send, 2);
      float keep = (lane & 2) ? ACC(8 + t) : ACC(t);
      ACC(t) = keep + recv;
    }
    #pragma unroll
    for (int t = 0; t < 4; ++t) {
      float send = (lane & 4) ? ACC(t) : ACC(4 + t);
      float recv = __shfl_xor(send, 4);
      float keep = (lane & 4) ? ACC(4 + t) : ACC(t);
      ACC(t) = keep + recv;
    }
    #pragma unroll
    for (int t = 0; t < 2; ++t) {
      float send = (lane & 8) ? ACC(t) : ACC(2 + t);
      float recv = __shfl_xor(send, 8);
      float keep = (lane & 8) ? ACC(2 + t) : ACC(t);
      ACC(t) = keep + recv;
    }
    {
      float send = (lane & 16) ? ACC(0) : ACC(1);
      float recv = __shfl_xor(send, 16);
      float keep = (lane & 16) ? ACC(1) : ACC(0);
      ACC(0) = keep + recv;
    }
    ACC(0) += __shfl_xor(ACC(0), 32);
    if (lane < 32) {
      int e = ((lane & 1) << 4) | ((lane & 2) << 2) | (lane & 4) |
              ((lane & 8) >> 2) | ((lane & 16) >> 4);
      opart[half][e] = ACC(0);
    }
    __syncthreads();
    if (tid < 32)
      xatt[((size_t)bt*LL + i)*CC + tid] = opart[0][tid] + opart[1][tid];
  }
}

// ---------------- Wm projection (4-way co-split); t<8 -> out, t==8 -> xm8 ----------------
// block (64,4): x = l-chunk lane, y = co-quarter. 576 blocks.
__global__ __launch_bounds__(256) void wm_kernel(
    const float* __restrict__ xatt, const float* __restrict__ Wm, const float* __restrict__ bm,
    float* __restrict__ out, float* __restrict__ xm8) {
  int gl = blockIdx.x * 64 + threadIdx.x;   // 0..36863
  int qy = threadIdx.y;                     // 0..3
  int l  = gl & (LL-1);
  int bt = gl >> 9;
  int b = bt / TT, t = bt - b*TT;
  float xv[CC];
  #pragma unroll
  for (int c = 0; c < CC; c += 4) {
    float4 x4 = *reinterpret_cast<const float4*>(&xatt[(size_t)gl*CC + c]);
    xv[c] = x4.x; xv[c+1] = x4.y; xv[c+2] = x4.z; xv[c+3] = x4.w;
  }
  #pragma unroll
  for (int u = 0; u < 8; ++u) {
    int co = qy*8 + u;
    float acc = bm[co];
    #pragma unroll
    for (int ci = 0; ci < CC; ++ci) acc += xv[ci] * Wm[co*CC + ci];
    if (t < TT-1) out[((b*CC + co)*TT + t)*LL + l] = acc;
    else          xm8[(b*CC + co)*LL + l] = acc;
  }
}

// ---------------- conv over (ci,t) + BN(eval) + ReLU ----------------
__global__ __launch_bounds__(512) void conv_kernel(
    const float* __restrict__ out, const float* __restrict__ pp,
    const float* __restrict__ cw, const float* __restrict__ cb,
    const float* __restrict__ bng, const float* __restrict__ bnb,
    float* __restrict__ yws) {
  int bc = blockIdx.x;            // b*32 + co
  int b = bc >> 5, co = bc & 31;
  int l = threadIdx.x;
  float acc = cb[co];
  #pragma unroll
  for (int ci = 0; ci < CC; ++ci) {
    const float* base = out + ((b*CC + ci)*TT)*LL + l;
    const float* w = cw + (co*CC + ci)*TT;
    #pragma unroll
    for (int t = 0; t < TT-1; ++t) acc += base[t*LL] * w[t];
    acc += pp[ci*LL + l] * w[TT-1];
  }
  float scale = bng[co] * 0.999995000037499687f;   // 1/sqrt(1+1e-5)
  float val = acc * scale + bnb[co];
  yws[bc*LL + l] = fmaxf(val, 0.f);
}

// ---------------- token-linear p = y @ pl_w.T + pl_b; out[t=8] = xm8 - p ----------------
__global__ __launch_bounds__(512) void pl_kernel(
    const float* __restrict__ yws, const float* __restrict__ plwT,
    const float* __restrict__ plb, const float* __restrict__ xm8,
    float* __restrict__ out) {
  __shared__ float sy[2][LL];
  int bc0 = blockIdx.x * 2;
  int tid = threadIdx.x;
  sy[0][tid] = yws[bc0*LL + tid];
  sy[1][tid] = yws[(bc0+1)*LL + tid];
  __syncthreads();
  float acc0 = plb[tid], acc1 = plb[tid];
  #pragma unroll 4
  for (int l = 0; l < LL; ++l) {
    float w = plwT[l*LL + tid];
    acc0 += sy[0][l] * w;
    acc1 += sy[1][l] * w;
  }
  out[(bc0*TT + (TT-1))*LL + tid]       = xm8[bc0*LL + tid] - acc0;
  out[((bc0+1)*TT + (TT-1))*LL + tid]   = xm8[(bc0+1)*LL + tid] - acc1;
}

extern "C" void kernel_launch(void* const* d_in, const int* in_sizes, int n_in,
                              void* d_out, int out_size, void* d_ws, size_t ws_size,
                              hipStream_t stream) {
  const float* x    = (const float*)d_in[0];
  const float* Wq   = (const float*)d_in[1];
  const float* bq   = (const float*)d_in[2];
  const float* Wk   = (const float*)d_in[3];
  const float* bk   = (const float*)d_in[4];
  const float* Wv   = (const float*)d_in[5];
  const float* bv   = (const float*)d_in[6];
  const float* Wm   = (const float*)d_in[7];
  const float* bm   = (const float*)d_in[8];
  const float* Wl   = (const float*)d_in[9];
  const float* Wc   = (const float*)d_in[10];
  const float* rpb  = (const float*)d_in[11];
  const float* pp   = (const float*)d_in[12];
  const float* cw   = (const float*)d_in[13];
  const float* cb   = (const float*)d_in[14];
  const float* bng  = (const float*)d_in[15];
  const float* bnb  = (const float*)d_in[16];
  const float* plw  = (const float*)d_in[17];
  const float* plb  = (const float*)d_in[18];
  float* out = (float*)d_out;

  float* ws = (float*)d_ws;
  const size_t QKV = (size_t)NBT*HH*LL*DD;     // 1179648
  float* q_ws   = ws;                 // QKV ([bt][h][l][d])
  float* k_ws   = q_ws + QKV;         // QKV ([bt][h][l][d])
  float* v_ws   = k_ws + QKV;         // QKV ([bt][h][l][d])
  float* xatt   = v_ws + QKV;         // NBT*LL*CC = 1179648
  float* xm8    = xatt + QKV;         // BB*CC*LL = 131072
  float* yws    = xm8 + (size_t)BB*CC*LL;      // 131072
  float* plwT   = yws + (size_t)BB*CC*LL;      // 262144
  float* mbias  = plwT + (size_t)LL*LL;        // 8*1024 reversed, log2e-scaled

  mixed_bias_kernel<<<2, 512, 0, stream>>>(rpb, Wl, mbias);
  transpose512_kernel<<<dim3(16,16), 256, 0, stream>>>(plw, plwT);
  proj_kernel<<<(BB*TT*LL)/256, 256, 0, stream>>>(x, Wq, bq, Wk, bk, Wv, bv, q_ws, k_ws, v_ws);
  attn_kernel<<<NBT*64, 128, 0, stream>>>(q_ws, k_ws, v_ws, Wl, Wc, mbias, xatt);
  wm_kernel<<<576, dim3(64,4), 0, stream>>>(xatt, Wm, bm, out, xm8);
  conv_kernel<<<BB*CC, LL, 0, stream>>>(out, pp, cw, cb, bng, bnb, yws);
  pl_kernel<<<(BB*CC)/2, LL, 0, stream>>>(yws, plwT, plb, xm8, out);
}

// Round 10
// 372.509 us; speedup vs baseline: 3.9190x; 2.0985x over previous
//
#include <hip/hip_runtime.h>
#include <math.h>

#define BB 8
#define CC 32
#define TT 9
#define LL 512
#define HH 8
#define DD 4
#define NBT (BB*TT)          // 72
#define RELN (2*LL-1)        // 1023
#define RLN2 1.4426950408889634f

typedef float v2f __attribute__((ext_vector_type(2)));

__device__ __forceinline__ float bflo(unsigned u) { return __uint_as_float(u << 16); }
__device__ __forceinline__ float bfhi(unsigned u) { return __uint_as_float(u & 0xffff0000u); }

// ---- mixed bias, reversed + log2e-prescaled: mbr[Ho][x] = log2e * sum_h rpb[h][1022-x] Wl[h][Ho]
__global__ void mixed_bias_kernel(const float* __restrict__ rpb,
                                  const float* __restrict__ Wl,
                                  float* __restrict__ mbr) {
  int x = blockIdx.x * blockDim.x + threadIdx.x;
  if (x >= RELN) return;
  int idx = 1022 - x;
  float r[HH];
  #pragma unroll
  for (int h = 0; h < HH; ++h) r[h] = rpb[h*RELN + idx];
  #pragma unroll
  for (int Ho = 0; Ho < HH; ++Ho) {
    float acc = 0.f;
    #pragma unroll
    for (int h = 0; h < HH; ++h) acc += r[h] * Wl[h*HH + Ho];
    mbr[Ho*1024 + x] = RLN2 * acc;
  }
}

// ---------------- transpose pl_w (512x512): outT[l][l'] = in[l'][l] ----------------
__global__ __launch_bounds__(256) void transpose512_kernel(const float* __restrict__ in,
                                                           float* __restrict__ outT) {
  __shared__ float tile[32][33];
  int bx = blockIdx.x * 32, by = blockIdx.y * 32;
  int tx = threadIdx.x & 31, ty = threadIdx.x >> 5;   // 32x8
  #pragma unroll
  for (int yy = ty; yy < 32; yy += 8)
    tile[yy][tx] = in[(by + yy)*LL + bx + tx];
  __syncthreads();
  #pragma unroll
  for (int yy = ty; yy < 32; yy += 8)
    outT[(bx + yy)*LL + by + tx] = tile[tx][yy];
}

// ---------------- q/k/v projection + l2norm ----------------
// q,k,v all [bt][h][l][d]; q scaled by 0.5*log2e (1/sqrt(D) + exp2 prescale folded in)
__global__ __launch_bounds__(256) void proj_kernel(
    const float* __restrict__ x,
    const float* __restrict__ Wq, const float* __restrict__ bq,
    const float* __restrict__ Wk, const float* __restrict__ bk,
    const float* __restrict__ Wv, const float* __restrict__ bv,
    float* __restrict__ qo, float* __restrict__ ko, float* __restrict__ vo) {
  int g = blockIdx.x * 256 + threadIdx.x;    // 0..36863
  int l  = g & (LL-1);
  int bt = g >> 9;
  int b = bt / TT, t = bt - b*TT;

  float xv[CC];
  #pragma unroll
  for (int c = 0; c < CC; ++c)
    xv[c] = x[((b*CC + c)*TT + t)*LL + l];

  const float* Ws[3] = {Wq, Wk, Wv};
  const float* bs[3] = {bq, bk, bv};
  float* ds[3] = {qo, ko, vo};
  #pragma unroll
  for (int p = 0; p < 3; ++p) {
    const float* W = Ws[p];
    const float* bi = bs[p];
    float* dst = ds[p];
    const float post = (p == 0) ? 0.5f * RLN2 : 1.0f;
    #pragma unroll
    for (int h = 0; h < HH; ++h) {
      float yv[DD];
      #pragma unroll
      for (int d = 0; d < DD; ++d) {
        int co = h*DD + d;
        float acc = bi[co];
        #pragma unroll
        for (int ci = 0; ci < CC; ++ci) acc += xv[ci] * W[co*CC + ci];
        yv[d] = acc;
      }
      float n = sqrtf(yv[0]*yv[0] + yv[1]*yv[1] + yv[2]*yv[2] + yv[3]*yv[3]);
      float inv = post / fmaxf(n, 1e-12f);
      float4 o4 = make_float4(yv[0]*inv, yv[1]*inv, yv[2]*inv, yv[3]*inv);
      *reinterpret_cast<float4*>(&dst[((size_t)(bt*HH + h))*(LL*DD) + l*DD]) = o4;
    }
  }
}

// ---------------- fused attention (v10: 256-thr, bf16 K in LDS -> 4 blocks/CU) ----------
// 2304 blocks x 256 thr (4 waves = 2 pairs). Pair owns 8 rows serially; per row,
// wave-half owns 256 j, each lane 4 j. K staged bf16 in LDS (32 KB, ds_read_b64 +
// shift/and unpack); V fp32 from L2 (per-lane, tight per-Hp batches -> no reg bloat).
// launch_bounds(256,2): cap 256, allocator lands ~120 -> NO spill (family needs >=128;
// NEVER declare caps < 128 here: 64-cap spilled 3.6 GB in r8).
#define ACC(e) acc2[(e)>>1][(e)&1]
__global__ __launch_bounds__(256, 2) void attn_kernel(
    const float* __restrict__ q, const float* __restrict__ k, const float* __restrict__ v,
    const float* __restrict__ Wl, const float* __restrict__ Wc,
    const float* __restrict__ mbr, float* __restrict__ xatt) {
  __shared__ unsigned k_lds[HH*LL*2];   // 32 KB bf16x2: (h,j) -> 2 uints (4 bf16)
  __shared__ float sS[4][HH];           // per-wave softmax partial sums
  __shared__ float opart[4][CC];        // per-wave PV partials

  // XCD swizzle: 2304 blocks, 288 per XCD = 9 bt (bijective)
  const int wgid = blockIdx.x;
  const int id   = (wgid & 7) * 288 + (wgid >> 3);
  const int bt   = id >> 5;     // [0,72)
  const int iblk = id & 31;     // [0,32): 16-row group

  const int tid  = threadIdx.x;
  const int wave = __builtin_amdgcn_readfirstlane(tid >> 6);   // 0..3
  const int lane = tid & 63;
  const int pair = wave >> 1;   // 0,1
  const int half = wave & 1;    // 0,1
  const int jbase = half*256 + lane;    // j = jbase + p*128 + {0,64}

  // ---- stage K -> LDS as bf16 (cvt_pk, RNE). 2048 j-pairs over 8 iters.
  {
    const float* kg = k + (size_t)bt*(HH*LL*DD);
    #pragma unroll
    for (int it = 0; it < 8; ++it) {
      int pi = it*256 + tid;          // 0..2047
      int h  = pi >> 8;
      int j0 = (pi & 255) * 2;
      float4 ka = *reinterpret_cast<const float4*>(&kg[(h*LL + j0)*DD]);
      float4 kc = *reinterpret_cast<const float4*>(&kg[(h*LL + j0 + 1)*DD]);
      unsigned u0, u1, u2, u3;
      asm("v_cvt_pk_bf16_f32 %0, %1, %2" : "=v"(u0) : "v"(ka.x), "v"(ka.y));
      asm("v_cvt_pk_bf16_f32 %0, %1, %2" : "=v"(u1) : "v"(ka.z), "v"(ka.w));
      asm("v_cvt_pk_bf16_f32 %0, %1, %2" : "=v"(u2) : "v"(kc.x), "v"(kc.y));
      asm("v_cvt_pk_bf16_f32 %0, %1, %2" : "=v"(u3) : "v"(kc.z), "v"(kc.w));
      uint4 u = make_uint4(u0, u1, u2, u3);
      *reinterpret_cast<uint4*>(&k_lds[(h*LL + j0)*2]) = u;
    }
  }
  __syncthreads();

  const float* vb = v + (size_t)bt*(HH*LL*DD);

  #pragma unroll 1
  for (int r = 0; r < 8; ++r) {
    const int i = iblk*16 + pair*8 + r;

    // ---- q row (uniform address -> broadcast loads)
    float4 qv[HH];
    {
      const float* qrow = q + (size_t)(bt*HH)*(LL*DD) + i*DD;
      #pragma unroll
      for (int h = 0; h < HH; ++h)
        qv[h] = *reinterpret_cast<const float4*>(&qrow[h*(LL*DD)]);
    }

    // ---- init logits with mixed rel-pos bias
    v2f lg2[HH][2];
    {
      const int ob = jbase - i + 511;
      #pragma unroll
      for (int H = 0; H < HH; ++H) {
        const float* m = &mbr[H*1024 + ob];
        lg2[H][0] = (v2f){ m[0],   m[64]  };
        lg2[H][1] = (v2f){ m[128], m[192] };
      }
    }

    // ---- scores + head-mix 1 (K from LDS bf16, unpack via shift/and)
    #pragma unroll
    for (int p = 0; p < 2; ++p) {
      const int j0 = jbase + p*128;
      v2f s2[HH];
      #pragma unroll
      for (int h = 0; h < HH; ++h) {
        uint2 a = *reinterpret_cast<const uint2*>(&k_lds[(h*LL + j0)*2]);
        uint2 c = *reinterpret_cast<const uint2*>(&k_lds[(h*LL + j0 + 64)*2]);
        s2[h][0] = qv[h].x*bflo(a.x) + qv[h].y*bfhi(a.x) + qv[h].z*bflo(a.y) + qv[h].w*bfhi(a.y);
        s2[h][1] = qv[h].x*bflo(c.x) + qv[h].y*bfhi(c.x) + qv[h].z*bflo(c.y) + qv[h].w*bfhi(c.y);
      }
      #pragma unroll
      for (int h = 0; h < HH; ++h) {
        #pragma unroll
        for (int H = 0; H < HH; ++H) {
          float w = Wl[h*HH + H];
          lg2[H][p] += s2[h] * (v2f){w, w};
        }
      }
    }

    // ---- exp + wave butterfly sum per head
    float Sown[HH];
    #pragma unroll
    for (int H = 0; H < HH; ++H) {
      v2f e0 = (v2f){ exp2f(lg2[H][0][0]), exp2f(lg2[H][0][1]) };
      v2f e1 = (v2f){ exp2f(lg2[H][1][0]), exp2f(lg2[H][1][1]) };
      lg2[H][0] = e0; lg2[H][1] = e1;
      float t = (e0[0] + e0[1]) + (e1[0] + e1[1]);
      #pragma unroll
      for (int off = 32; off >= 1; off >>= 1) t += __shfl_xor(t, off);
      Sown[H] = t;
    }
    if (lane == 0) {
      *reinterpret_cast<float4*>(&sS[wave][0]) = make_float4(Sown[0], Sown[1], Sown[2], Sown[3]);
      *reinterpret_cast<float4*>(&sS[wave][4]) = make_float4(Sown[4], Sown[5], Sown[6], Sown[7]);
    }
    __syncthreads();
    {
      const int pw = wave ^ 1;
      #pragma unroll
      for (int H = 0; H < HH; ++H) {
        float inv = __builtin_amdgcn_rcpf(Sown[H] + sS[pw][H]);
        lg2[H][0] *= (v2f){inv, inv};
        lg2[H][1] *= (v2f){inv, inv};
      }
    }

    // ---- head-mix 2 + PV (V fp32 from L2, per-Hp tight batches)
    v2f acc2[16];
    #pragma unroll
    for (int e = 0; e < 16; ++e) acc2[e] = (v2f){0.f, 0.f};
    #pragma unroll
    for (int p = 0; p < 2; ++p) {
      const int j0 = jbase + p*128;
      #pragma unroll
      for (int Hp = 0; Hp < HH; ++Hp) {
        v2f a2;
        {
          float w = Wc[Hp];
          a2 = lg2[0][p] * (v2f){w, w};
        }
        #pragma unroll
        for (int H = 1; H < HH; ++H) {
          float w = Wc[H*HH + Hp];
          a2 += lg2[H][p] * (v2f){w, w};
        }
        float4 va = *reinterpret_cast<const float4*>(&vb[(Hp*LL + j0)*DD]);
        float4 vc = *reinterpret_cast<const float4*>(&vb[(Hp*LL + j0 + 64)*DD]);
        acc2[Hp*2+0] += (v2f){a2[0], a2[0]} * (v2f){va.x, va.y}
                      + (v2f){a2[1], a2[1]} * (v2f){vc.x, vc.y};
        acc2[Hp*2+1] += (v2f){a2[0], a2[0]} * (v2f){va.z, va.w}
                      + (v2f){a2[1], a2[1]} * (v2f){vc.z, vc.w};
      }
    }

    // ---- fold reduction: 32 values over 64 lanes (exchange-and-halve)
    #pragma unroll
    for (int t = 0; t < 16; ++t) {
      float send = (lane & 1) ? ACC(t) : ACC(16 + t);
      float recv = __shfl_xor(send, 1);
      float keep = (lane & 1) ? ACC(16 + t) : ACC(t);
      ACC(t) = keep + recv;
    }
    #pragma unroll
    for (int t = 0; t < 8; ++t) {
      float send = (lane & 2) ? ACC(t) : ACC(8 + t);
      float recv = __shfl_xor(send, 2);
      float keep = (lane & 2) ? ACC(8 + t) : ACC(t);
      ACC(t) = keep + recv;
    }
    #pragma unroll
    for (int t = 0; t < 4; ++t) {
      float send = (lane & 4) ? ACC(t) : ACC(4 + t);
      float recv = __shfl_xor(send, 4);
      float keep = (lane & 4) ? ACC(4 + t) : ACC(t);
      ACC(t) = keep + recv;
    }
    #pragma unroll
    for (int t = 0; t < 2; ++t) {
      float send = (lane & 8) ? ACC(t) : ACC(2 + t);
      float recv = __shfl_xor(send, 8);
      float keep = (lane & 8) ? ACC(2 + t) : ACC(t);
      ACC(t) = keep + recv;
    }
    {
      float send = (lane & 16) ? ACC(0) : ACC(1);
      float recv = __shfl_xor(send, 16);
      float keep = (lane & 16) ? ACC(1) : ACC(0);
      ACC(0) = keep + recv;
    }
    ACC(0) += __shfl_xor(ACC(0), 32);
    if (lane < 32) {
      int e = ((lane & 1) << 4) | ((lane & 2) << 2) | (lane & 4) |
              ((lane & 8) >> 2) | ((lane & 16) >> 4);
      opart[wave][e] = ACC(0);
    }
    __syncthreads();
    if (half == 0 && lane < 32)
      xatt[((size_t)bt*LL + i)*CC + lane] = opart[wave][lane] + opart[wave + 1][lane];
  }
}

// ---------------- Wm projection (4-way co-split); t<8 -> out, t==8 -> xm8 ----------------
__global__ __launch_bounds__(256) void wm_kernel(
    const float* __restrict__ xatt, const float* __restrict__ Wm, const float* __restrict__ bm,
    float* __restrict__ out, float* __restrict__ xm8) {
  int gl = blockIdx.x * 64 + threadIdx.x;   // 0..36863
  int qy = threadIdx.y;                     // 0..3
  int l  = gl & (LL-1);
  int bt = gl >> 9;
  int b = bt / TT, t = bt - b*TT;
  float xv[CC];
  #pragma unroll
  for (int c = 0; c < CC; c += 4) {
    float4 x4 = *reinterpret_cast<const float4*>(&xatt[(size_t)gl*CC + c]);
    xv[c] = x4.x; xv[c+1] = x4.y; xv[c+2] = x4.z; xv[c+3] = x4.w;
  }
  #pragma unroll
  for (int u = 0; u < 8; ++u) {
    int co = qy*8 + u;
    float acc = bm[co];
    #pragma unroll
    for (int ci = 0; ci < CC; ++ci) acc += xv[ci] * Wm[co*CC + ci];
    if (t < TT-1) out[((b*CC + co)*TT + t)*LL + l] = acc;
    else          xm8[(b*CC + co)*LL + l] = acc;
  }
}

// ---------------- conv over (ci,t) + BN(eval) + ReLU ----------------
__global__ __launch_bounds__(512) void conv_kernel(
    const float* __restrict__ out, const float* __restrict__ pp,
    const float* __restrict__ cw, const float* __restrict__ cb,
    const float* __restrict__ bng, const float* __restrict__ bnb,
    float* __restrict__ yws) {
  int bc = blockIdx.x;            // b*32 + co
  int b = bc >> 5, co = bc & 31;
  int l = threadIdx.x;
  float acc = cb[co];
  #pragma unroll
  for (int ci = 0; ci < CC; ++ci) {
    const float* base = out + ((b*CC + ci)*TT)*LL + l;
    const float* w = cw + (co*CC + ci)*TT;
    #pragma unroll
    for (int t = 0; t < TT-1; ++t) acc += base[t*LL] * w[t];
    acc += pp[ci*LL + l] * w[TT-1];
  }
  float scale = bng[co] * 0.999995000037499687f;   // 1/sqrt(1+1e-5)
  float val = acc * scale + bnb[co];
  yws[bc*LL + l] = fmaxf(val, 0.f);
}

// ---------------- token-linear p = y @ pl_w.T + pl_b; out[t=8] = xm8 - p ----------------
__global__ __launch_bounds__(512) void pl_kernel(
    const float* __restrict__ yws, const float* __restrict__ plwT,
    const float* __restrict__ plb, const float* __restrict__ xm8,
    float* __restrict__ out) {
  __shared__ float sy[2][LL];
  int bc0 = blockIdx.x * 2;
  int tid = threadIdx.x;
  sy[0][tid] = yws[bc0*LL + tid];
  sy[1][tid] = yws[(bc0+1)*LL + tid];
  __syncthreads();
  float acc0 = plb[tid], acc1 = plb[tid];
  #pragma unroll 4
  for (int l = 0; l < LL; ++l) {
    float w = plwT[l*LL + tid];
    acc0 += sy[0][l] * w;
    acc1 += sy[1][l] * w;
  }
  out[(bc0*TT + (TT-1))*LL + tid]       = xm8[bc0*LL + tid] - acc0;
  out[((bc0+1)*TT + (TT-1))*LL + tid]   = xm8[(bc0+1)*LL + tid] - acc1;
}

extern "C" void kernel_launch(void* const* d_in, const int* in_sizes, int n_in,
                              void* d_out, int out_size, void* d_ws, size_t ws_size,
                              hipStream_t stream) {
  const float* x    = (const float*)d_in[0];
  const float* Wq   = (const float*)d_in[1];
  const float* bq   = (const float*)d_in[2];
  const float* Wk   = (const float*)d_in[3];
  const float* bk   = (const float*)d_in[4];
  const float* Wv   = (const float*)d_in[5];
  const float* bv   = (const float*)d_in[6];
  const float* Wm   = (const float*)d_in[7];
  const float* bm   = (const float*)d_in[8];
  const float* Wl   = (const float*)d_in[9];
  const float* Wc   = (const float*)d_in[10];
  const float* rpb  = (const float*)d_in[11];
  const float* pp   = (const float*)d_in[12];
  const float* cw   = (const float*)d_in[13];
  const float* cb   = (const float*)d_in[14];
  const float* bng  = (const float*)d_in[15];
  const float* bnb  = (const float*)d_in[16];
  const float* plw  = (const float*)d_in[17];
  const float* plb  = (const float*)d_in[18];
  float* out = (float*)d_out;

  float* ws = (float*)d_ws;
  const size_t QKV = (size_t)NBT*HH*LL*DD;     // 1179648
  float* q_ws   = ws;                 // QKV ([bt][h][l][d])
  float* k_ws   = q_ws + QKV;         // QKV ([bt][h][l][d])
  float* v_ws   = k_ws + QKV;         // QKV ([bt][h][l][d])
  float* xatt   = v_ws + QKV;         // NBT*LL*CC = 1179648
  float* xm8    = xatt + QKV;         // BB*CC*LL = 131072
  float* yws    = xm8 + (size_t)BB*CC*LL;      // 131072
  float* plwT   = yws + (size_t)BB*CC*LL;      // 262144
  float* mbias  = plwT + (size_t)LL*LL;        // 8*1024 reversed, log2e-scaled

  mixed_bias_kernel<<<2, 512, 0, stream>>>(rpb, Wl, mbias);
  transpose512_kernel<<<dim3(16,16), 256, 0, stream>>>(plw, plwT);
  proj_kernel<<<(BB*TT*LL)/256, 256, 0, stream>>>(x, Wq, bq, Wk, bk, Wv, bv, q_ws, k_ws, v_ws);
  attn_kernel<<<NBT*32, 256, 0, stream>>>(q_ws, k_ws, v_ws, Wl, Wc, mbias, xatt);
  wm_kernel<<<576, dim3(64,4), 0, stream>>>(xatt, Wm, bm, out, xm8);
  conv_kernel<<<BB*CC, LL, 0, stream>>>(out, pp, cw, cb, bng, bnb, yws);
  pl_kernel<<<(BB*CC)/2, LL, 0, stream>>>(yws, plwT, plb, xm8, out);
}

// Round 11
// 243.377 us; speedup vs baseline: 5.9983x; 1.5306x over previous
//
#include <hip/hip_runtime.h>
#include <math.h>

#define BB 8
#define CC 32
#define TT 9
#define LL 512
#define HH 8
#define DD 4
#define NBT (BB*TT)          // 72
#define RELN (2*LL-1)        // 1023
#define RLN2 1.4426950408889634f

typedef float  f4v __attribute__((ext_vector_type(4)));
typedef int    i4v __attribute__((ext_vector_type(4)));
typedef short  s8v __attribute__((ext_vector_type(8)));   // 8 bf16 = 4 VGPRs

__device__ __forceinline__ unsigned cvtpk(float lo, float hi) {
  unsigned u;
  asm("v_cvt_pk_bf16_f32 %0, %1, %2" : "=v"(u) : "v"(lo), "v"(hi));
  return u;
}

// ---- mixed bias, reversed + log2e-prescaled: mbr[Ho][x] = log2e * sum_h rpb[h][1022-x] Wl[h][Ho]
// (consumer index: x = j - i + 511  <=>  rel idx i - j + 511 = 1022 - x)
__global__ void mixed_bias_kernel(const float* __restrict__ rpb,
                                  const float* __restrict__ Wl,
                                  float* __restrict__ mbr) {
  int x = blockIdx.x * blockDim.x + threadIdx.x;
  if (x >= RELN) return;
  int idx = 1022 - x;
  float r[HH];
  #pragma unroll
  for (int h = 0; h < HH; ++h) r[h] = rpb[h*RELN + idx];
  #pragma unroll
  for (int Ho = 0; Ho < HH; ++Ho) {
    float acc = 0.f;
    #pragma unroll
    for (int h = 0; h < HH; ++h) acc += r[h] * Wl[h*HH + Ho];
    mbr[Ho*1024 + x] = RLN2 * acc;
  }
}

// ---------------- transpose pl_w (512x512): outT[l][l'] = in[l'][l] ----------------
__global__ __launch_bounds__(256) void transpose512_kernel(const float* __restrict__ in,
                                                           float* __restrict__ outT) {
  __shared__ float tile[32][33];
  int bx = blockIdx.x * 32, by = blockIdx.y * 32;
  int tx = threadIdx.x & 31, ty = threadIdx.x >> 5;   // 32x8
  #pragma unroll
  for (int yy = ty; yy < 32; yy += 8)
    tile[yy][tx] = in[(by + yy)*LL + bx + tx];
  __syncthreads();
  #pragma unroll
  for (int yy = ty; yy < 32; yy += 8)
    outT[(bx + yy)*LL + by + tx] = tile[tx][yy];
}

// ---------------- q/k/v projection + l2norm ----------------
// qo fp32 [bt][l][32] scaled by 0.5*log2e; kbo bf16 [bt][l][32]; vbo fp32 [bt][l][32]
__global__ __launch_bounds__(256) void proj_kernel(
    const float* __restrict__ x,
    const float* __restrict__ Wq, const float* __restrict__ bq,
    const float* __restrict__ Wk, const float* __restrict__ bk,
    const float* __restrict__ Wv, const float* __restrict__ bv,
    float* __restrict__ qo, short* __restrict__ kbo, float* __restrict__ vbo) {
  int gidx = blockIdx.x * 256 + threadIdx.x;    // 0..36863
  int l  = gidx & (LL-1);
  int bt = gidx >> 9;
  int b = bt / TT, t = bt - b*TT;

  float xv[CC];
  #pragma unroll
  for (int c = 0; c < CC; ++c)
    xv[c] = x[((b*CC + c)*TT + t)*LL + l];

  // Q (scaled by 0.5*log2e = 1/sqrt(D) + exp2 prescale)
  #pragma unroll
  for (int h = 0; h < HH; ++h) {
    float yv[DD];
    #pragma unroll
    for (int d = 0; d < DD; ++d) {
      int co = h*DD + d;
      float acc = bq[co];
      #pragma unroll
      for (int ci = 0; ci < CC; ++ci) acc += xv[ci] * Wq[co*CC + ci];
      yv[d] = acc;
    }
    float n = sqrtf(yv[0]*yv[0] + yv[1]*yv[1] + yv[2]*yv[2] + yv[3]*yv[3]);
    float inv = 0.5f * RLN2 / fmaxf(n, 1e-12f);
    *reinterpret_cast<float4*>(&qo[((size_t)bt*LL + l)*CC + h*DD]) =
        make_float4(yv[0]*inv, yv[1]*inv, yv[2]*inv, yv[3]*inv);
  }
  // K -> bf16
  {
    unsigned ku[16];
    #pragma unroll
    for (int h = 0; h < HH; ++h) {
      float yv[DD];
      #pragma unroll
      for (int d = 0; d < DD; ++d) {
        int co = h*DD + d;
        float acc = bk[co];
        #pragma unroll
        for (int ci = 0; ci < CC; ++ci) acc += xv[ci] * Wk[co*CC + ci];
        yv[d] = acc;
      }
      float n = sqrtf(yv[0]*yv[0] + yv[1]*yv[1] + yv[2]*yv[2] + yv[3]*yv[3]);
      float inv = 1.0f / fmaxf(n, 1e-12f);
      ku[h*2]   = cvtpk(yv[0]*inv, yv[1]*inv);
      ku[h*2+1] = cvtpk(yv[2]*inv, yv[3]*inv);
    }
    uint4* kd = reinterpret_cast<uint4*>(kbo + ((size_t)bt*LL + l)*CC);
    #pragma unroll
    for (int wq4 = 0; wq4 < 4; ++wq4)
      kd[wq4] = make_uint4(ku[wq4*4], ku[wq4*4+1], ku[wq4*4+2], ku[wq4*4+3]);
  }
  // V fp32 [bt][l][32]
  #pragma unroll
  for (int h = 0; h < HH; ++h) {
    float yv[DD];
    #pragma unroll
    for (int d = 0; d < DD; ++d) {
      int co = h*DD + d;
      float acc = bv[co];
      #pragma unroll
      for (int ci = 0; ci < CC; ++ci) acc += xv[ci] * Wv[co*CC + ci];
      yv[d] = acc;
    }
    float n = sqrtf(yv[0]*yv[0] + yv[1]*yv[1] + yv[2]*yv[2] + yv[3]*yv[3]);
    float inv = 1.0f / fmaxf(n, 1e-12f);
    *reinterpret_cast<float4*>(&vbo[((size_t)bt*LL + l)*CC + h*DD]) =
        make_float4(yv[0]*inv, yv[1]*inv, yv[2]*inv, yv[3]*inv);
  }
}

// ---------------- Vt: VbT[bt][n=32][j=512] bf16 = vbo[bt][j][n] transposed ----------------
__global__ __launch_bounds__(256) void vbt_kernel(const float* __restrict__ vbo,
                                                  short* __restrict__ vt) {
  int bt = blockIdx.x;
  int n  = threadIdx.x & 31;
  int jc = threadIdx.x >> 5;          // 0..7, chunk of 64 j
  const float* src = vbo + ((size_t)bt*LL)*CC + n;
  int j0 = jc*64;
  unsigned u[32];
  #pragma unroll
  for (int jj = 0; jj < 32; ++jj) {
    float a = src[(size_t)(j0 + 2*jj)*CC];
    float b = src[(size_t)(j0 + 2*jj + 1)*CC];
    u[jj] = cvtpk(a, b);
  }
  uint4* dst = reinterpret_cast<uint4*>(vt + ((size_t)bt*CC + n)*LL + j0);
  #pragma unroll
  for (int wq = 0; wq < 8; ++wq)
    dst[wq] = make_uint4(u[wq*4], u[wq*4+1], u[wq*4+2], u[wq*4+3]);
}

// ---------------- fused attention (v11: MFMA) ----------------
// 1152 blocks x 256 thr. Block = (bt, 32-row i-block). Wave w: i-tile = iblk*32+(w&1)*16,
// heads H = (w>>1)*4 .. +3. Per (H, 32-j window): 2 swapped-QK mfma (A=K, B=QM=Wl-mixed q,
// C=bias) -> exp2 -> cvt_pk -> 8 ds_bpermute build PV A-frag -> 2 PV mfma vs bf16 V^T.
// Epilogue: denom xor-reduce + bpermute redistribute; scale by (Wc[H,H']/S_H). One barrier
// (H-half combine). Layout facts: C/D col=lane&15,row=(lane>>4)*4+r [m89]; A[m=lane&15]
// [k=(lane>>4)*8+e]; B[k=(lane>>4)*8+e][n=lane&15].
__global__ __launch_bounds__(256, 2) void attn_kernel(
    const float* __restrict__ q, const short* __restrict__ kb,
    const short* __restrict__ vt,
    const float* __restrict__ Wl, const float* __restrict__ Wc,
    const float* __restrict__ mbr, float* __restrict__ xatt) {
  __shared__ float xch[2][64][9];   // H-hi partials, padded (conflict-free)

  const int wgid = blockIdx.x;
  const int id   = (wgid & 7) * 144 + (wgid >> 3);   // 1152 % 8 == 0 -> bijective
  const int bt   = id >> 4;       // [0,72)
  const int iblk = id & 15;       // 32-row block

  const int tid  = threadIdx.x;
  const int w    = __builtin_amdgcn_readfirstlane(tid >> 6);
  const int lane = tid & 63;
  const int g    = lane >> 4;     // 0..3
  const int c16  = lane & 15;
  const int it   = iblk*32 + (w & 1)*16;   // wave's i-tile base
  const int Hb   = (w >> 1)*4;

  // q fragment source (fp32): q[it+c16][ g*8 .. g*8+7 ]
  float qp[8];
  {
    const float* qr = q + ((size_t)bt*LL + it + c16)*CC + g*8;
    float4 qa = *reinterpret_cast<const float4*>(qr);
    float4 qb = *reinterpret_cast<const float4*>(qr + 4);
    qp[0]=qa.x; qp[1]=qa.y; qp[2]=qa.z; qp[3]=qa.w;
    qp[4]=qb.x; qp[5]=qb.y; qp[6]=qb.z; qp[7]=qb.w;
  }
  const int h0 = g*2;                       // heads covered by this lane's k-chunk
  const short* kbase = kb + ((size_t)bt*LL)*CC;
  const short* vb0 = vt + ((size_t)bt*CC)*LL + (size_t)c16*LL;
  const short* vb1 = vb0 + 16*LL;

  f4v fin0 = {0.f,0.f,0.f,0.f}, fin1 = {0.f,0.f,0.f,0.f};
  const int s0b  = (c16 + 32*(g & 1))*4;    // bpermute byte addrs
  const int s1b  = s0b + 64;
  const bool useA = (g < 2);

  #pragma unroll 1
  for (int hh = 0; hh < 4; ++hh) {
    const int H = Hb + hh;
    const float wla  = Wl[h0*HH + H];
    const float wlb  = Wl[(h0+1)*HH + H];
    const float wclo = Wc[H*HH + (c16 >> 2)];
    const float wchi = Wc[H*HH + 4 + (c16 >> 2)];

    // QM b-frag: B[k=c][n=i] = Wl[h(c)][H] * q[i][c]
    s8v bq;
    {
      i4v uq;
      uq[0] = (int)cvtpk(qp[0]*wla, qp[1]*wla);
      uq[1] = (int)cvtpk(qp[2]*wla, qp[3]*wla);
      uq[2] = (int)cvtpk(qp[4]*wlb, qp[5]*wlb);
      uq[3] = (int)cvtpk(qp[6]*wlb, qp[7]*wlb);
      bq = __builtin_bit_cast(s8v, uq);
    }

    const float* mrow = mbr + H*1024 + 511 + 4*g - it - c16;

    f4v t0 = {0.f,0.f,0.f,0.f}, t1 = {0.f,0.f,0.f,0.f};
    float den = 0.f;

    #pragma unroll 1
    for (int jp = 0; jp < 16; ++jp) {
      const int j0 = jp*32;
      unsigned uA0, uA1, uB0, uB1;
      {
        s8v ak = *reinterpret_cast<const s8v*>(kbase + (size_t)(j0 + c16)*CC + g*8);
        f4v cb = { mrow[j0], mrow[j0+1], mrow[j0+2], mrow[j0+3] };
        f4v d = __builtin_amdgcn_mfma_f32_16x16x32_bf16(ak, bq, cb, 0, 0, 0);
        float e0 = exp2f(d[0]), e1 = exp2f(d[1]), e2 = exp2f(d[2]), e3 = exp2f(d[3]);
        den += (e0 + e1) + (e2 + e3);
        uA0 = cvtpk(e0, e1); uA1 = cvtpk(e2, e3);
      }
      {
        const int jt = j0 + 16;
        s8v ak = *reinterpret_cast<const s8v*>(kbase + (size_t)(jt + c16)*CC + g*8);
        f4v cb = { mrow[jt], mrow[jt+1], mrow[jt+2], mrow[jt+3] };
        f4v d = __builtin_amdgcn_mfma_f32_16x16x32_bf16(ak, bq, cb, 0, 0, 0);
        float e0 = exp2f(d[0]), e1 = exp2f(d[1]), e2 = exp2f(d[2]), e3 = exp2f(d[3]);
        den += (e0 + e1) + (e2 + e3);
        uB0 = cvtpk(e0, e1); uB1 = cvtpk(e2, e3);
      }
      // Build PV A-frag: lane needs P[i=c16][jl=8g..8g+7]; sources = lanes c16+32(g&1), +16;
      // tile A for g<2, tile B for g>=2.
      int a00 = __builtin_amdgcn_ds_bpermute(s0b, (int)uA0);
      int b00 = __builtin_amdgcn_ds_bpermute(s0b, (int)uB0);
      int a01 = __builtin_amdgcn_ds_bpermute(s0b, (int)uA1);
      int b01 = __builtin_amdgcn_ds_bpermute(s0b, (int)uB1);
      int a10 = __builtin_amdgcn_ds_bpermute(s1b, (int)uA0);
      int b10 = __builtin_amdgcn_ds_bpermute(s1b, (int)uB0);
      int a11 = __builtin_amdgcn_ds_bpermute(s1b, (int)uA1);
      int b11 = __builtin_amdgcn_ds_bpermute(s1b, (int)uB1);
      i4v pv;
      pv[0] = useA ? a00 : b00;
      pv[1] = useA ? a01 : b01;
      pv[2] = useA ? a10 : b10;
      pv[3] = useA ? a11 : b11;
      s8v pa = __builtin_bit_cast(s8v, pv);

      s8v v0 = *reinterpret_cast<const s8v*>(vb0 + j0 + 8*g);
      s8v v1 = *reinterpret_cast<const s8v*>(vb1 + j0 + 8*g);
      t0 = __builtin_amdgcn_mfma_f32_16x16x32_bf16(pa, v0, t0, 0, 0, 0);
      t1 = __builtin_amdgcn_mfma_f32_16x16x32_bf16(pa, v1, t1, 0, 0, 0);
    }

    // denominator: lane partial covers j = 4g..4g+3 (mod 16); reduce across groups
    den += __shfl_xor(den, 16);
    den += __shfl_xor(den, 32);
    float inv = __builtin_amdgcn_rcpf(den);   // S_H[i=c16] for all lanes
    #pragma unroll
    for (int r = 0; r < 4; ++r) {
      // temp rows are i_loc = 4g+r -> fetch inv for that i from lane 4g+r
      float ir = __int_as_float(
          __builtin_amdgcn_ds_bpermute((4*g + r)*4, __float_as_int(inv)));
      fin0[r] += t0[r] * (ir * wclo);
      fin1[r] += t1[r] * (ir * wchi);
    }
  }

  // combine H-halves (waves 2,3 -> 0,1), then coalesced write
  if (w >= 2) {
    #pragma unroll
    for (int r = 0; r < 4; ++r) {
      xch[w-2][lane][r]     = fin0[r];
      xch[w-2][lane][4 + r] = fin1[r];
    }
  }
  __syncthreads();
  if (w < 2) {
    #pragma unroll
    for (int r = 0; r < 4; ++r) {
      float o0 = fin0[r] + xch[w][lane][r];
      float o1 = fin1[r] + xch[w][lane][4 + r];
      const int i = it + 4*g + r;
      xatt[((size_t)bt*LL + i)*CC + c16]      = o0;
      xatt[((size_t)bt*LL + i)*CC + 16 + c16] = o1;
    }
  }
}

// ---------------- Wm projection (4-way co-split); t<8 -> out, t==8 -> xm8 ----------------
__global__ __launch_bounds__(256) void wm_kernel(
    const float* __restrict__ xatt, const float* __restrict__ Wm, const float* __restrict__ bm,
    float* __restrict__ out, float* __restrict__ xm8) {
  int gl = blockIdx.x * 64 + threadIdx.x;   // 0..36863
  int qy = threadIdx.y;                     // 0..3
  int l  = gl & (LL-1);
  int bt = gl >> 9;
  int b = bt / TT, t = bt - b*TT;
  float xv[CC];
  #pragma unroll
  for (int c = 0; c < CC; c += 4) {
    float4 x4 = *reinterpret_cast<const float4*>(&xatt[(size_t)gl*CC + c]);
    xv[c] = x4.x; xv[c+1] = x4.y; xv[c+2] = x4.z; xv[c+3] = x4.w;
  }
  #pragma unroll
  for (int u = 0; u < 8; ++u) {
    int co = qy*8 + u;
    float acc = bm[co];
    #pragma unroll
    for (int ci = 0; ci < CC; ++ci) acc += xv[ci] * Wm[co*CC + ci];
    if (t < TT-1) out[((b*CC + co)*TT + t)*LL + l] = acc;
    else          xm8[(b*CC + co)*LL + l] = acc;
  }
}

// ---------------- conv over (ci,t) + BN(eval) + ReLU ----------------
__global__ __launch_bounds__(512) void conv_kernel(
    const float* __restrict__ out, const float* __restrict__ pp,
    const float* __restrict__ cw, const float* __restrict__ cb,
    const float* __restrict__ bng, const float* __restrict__ bnb,
    float* __restrict__ yws) {
  int bc = blockIdx.x;            // b*32 + co
  int b = bc >> 5, co = bc & 31;
  int l = threadIdx.x;
  float acc = cb[co];
  #pragma unroll
  for (int ci = 0; ci < CC; ++ci) {
    const float* base = out + ((b*CC + ci)*TT)*LL + l;
    const float* wv = cw + (co*CC + ci)*TT;
    #pragma unroll
    for (int t = 0; t < TT-1; ++t) acc += base[t*LL] * wv[t];
    acc += pp[ci*LL + l] * wv[TT-1];
  }
  float scale = bng[co] * 0.999995000037499687f;   // 1/sqrt(1+1e-5)
  float val = acc * scale + bnb[co];
  yws[bc*LL + l] = fmaxf(val, 0.f);
}

// ---------------- token-linear p = y @ pl_w.T + pl_b; out[t=8] = xm8 - p ----------------
__global__ __launch_bounds__(512) void pl_kernel(
    const float* __restrict__ yws, const float* __restrict__ plwT,
    const float* __restrict__ plb, const float* __restrict__ xm8,
    float* __restrict__ out) {
  __shared__ float sy[2][LL];
  int bc0 = blockIdx.x * 2;
  int tid = threadIdx.x;
  sy[0][tid] = yws[bc0*LL + tid];
  sy[1][tid] = yws[(bc0+1)*LL + tid];
  __syncthreads();
  float acc0 = plb[tid], acc1 = plb[tid];
  #pragma unroll 4
  for (int l = 0; l < LL; ++l) {
    float wv = plwT[l*LL + tid];
    acc0 += sy[0][l] * wv;
    acc1 += sy[1][l] * wv;
  }
  out[(bc0*TT + (TT-1))*LL + tid]       = xm8[bc0*LL + tid] - acc0;
  out[((bc0+1)*TT + (TT-1))*LL + tid]   = xm8[(bc0+1)*LL + tid] - acc1;
}

extern "C" void kernel_launch(void* const* d_in, const int* in_sizes, int n_in,
                              void* d_out, int out_size, void* d_ws, size_t ws_size,
                              hipStream_t stream) {
  const float* x    = (const float*)d_in[0];
  const float* Wq   = (const float*)d_in[1];
  const float* bq   = (const float*)d_in[2];
  const float* Wk   = (const float*)d_in[3];
  const float* bk   = (const float*)d_in[4];
  const float* Wv   = (const float*)d_in[5];
  const float* bv   = (const float*)d_in[6];
  const float* Wm   = (const float*)d_in[7];
  const float* bm   = (const float*)d_in[8];
  const float* Wl   = (const float*)d_in[9];
  const float* Wc   = (const float*)d_in[10];
  const float* rpb  = (const float*)d_in[11];
  const float* pp   = (const float*)d_in[12];
  const float* cw   = (const float*)d_in[13];
  const float* cb   = (const float*)d_in[14];
  const float* bng  = (const float*)d_in[15];
  const float* bnb  = (const float*)d_in[16];
  const float* plw  = (const float*)d_in[17];
  const float* plb  = (const float*)d_in[18];
  float* out = (float*)d_out;

  float* ws = (float*)d_ws;
  const size_t NE = (size_t)NBT*LL*CC;         // 1179648
  float* q_ws   = ws;                          // NE fp32 [bt][l][32]
  float* vb_ws  = q_ws + NE;                   // NE fp32 [bt][l][32]
  short* kb_ws  = (short*)(vb_ws + NE);        // NE bf16 [bt][l][32]
  short* vt_ws  = kb_ws + NE;                  // NE bf16 [bt][32][512]
  float* xatt   = (float*)(vt_ws + NE);        // NE fp32
  float* xm8    = xatt + NE;                   // 131072
  float* yws    = xm8 + (size_t)BB*CC*LL;      // 131072
  float* plwT   = yws + (size_t)BB*CC*LL;      // 262144
  float* mbias  = plwT + (size_t)LL*LL;        // 8*1024

  mixed_bias_kernel<<<2, 512, 0, stream>>>(rpb, Wl, mbias);
  transpose512_kernel<<<dim3(16,16), 256, 0, stream>>>(plw, plwT);
  proj_kernel<<<(BB*TT*LL)/256, 256, 0, stream>>>(x, Wq, bq, Wk, bk, Wv, bv,
                                                  q_ws, kb_ws, vb_ws);
  vbt_kernel<<<NBT, 256, 0, stream>>>(vb_ws, vt_ws);
  attn_kernel<<<NBT*16, 256, 0, stream>>>(q_ws, kb_ws, vt_ws, Wl, Wc, mbias, xatt);
  wm_kernel<<<576, dim3(64,4), 0, stream>>>(xatt, Wm, bm, out, xm8);
  conv_kernel<<<BB*CC, LL, 0, stream>>>(out, pp, cw, cb, bng, bnb, yws);
  pl_kernel<<<(BB*CC)/2, LL, 0, stream>>>(yws, plwT, plb, xm8, out);
}

// Round 12
// 141.255 us; speedup vs baseline: 10.3348x; 1.7230x over previous
//
#include <hip/hip_runtime.h>
#include <math.h>

#define BB 8
#define CC 32
#define TT 9
#define LL 512
#define HH 8
#define DD 4
#define NBT (BB*TT)          // 72
#define RELN (2*LL-1)        // 1023
#define RLN2 1.4426950408889634f

typedef float  f4v __attribute__((ext_vector_type(4)));
typedef int    i4v __attribute__((ext_vector_type(4)));
typedef short  s8v __attribute__((ext_vector_type(8)));   // 8 bf16 = 4 VGPRs

__device__ __forceinline__ unsigned cvtpk(float lo, float hi) {
  unsigned u;
  asm("v_cvt_pk_bf16_f32 %0, %1, %2" : "=v"(u) : "v"(lo), "v"(hi));
  return u;
}

// ---- mixed bias, reversed + log2e-prescaled: mbr[Ho][x] = log2e * sum_h rpb[h][1022-x] Wl[h][Ho]
__global__ void mixed_bias_kernel(const float* __restrict__ rpb,
                                  const float* __restrict__ Wl,
                                  float* __restrict__ mbr) {
  int x = blockIdx.x * blockDim.x + threadIdx.x;
  if (x >= RELN) return;
  int idx = 1022 - x;
  float r[HH];
  #pragma unroll
  for (int h = 0; h < HH; ++h) r[h] = rpb[h*RELN + idx];
  #pragma unroll
  for (int Ho = 0; Ho < HH; ++Ho) {
    float acc = 0.f;
    #pragma unroll
    for (int h = 0; h < HH; ++h) acc += r[h] * Wl[h*HH + Ho];
    mbr[Ho*1024 + x] = RLN2 * acc;
  }
}

// ---------------- transpose pl_w (512x512): outT[l][l'] = in[l'][l] ----------------
__global__ __launch_bounds__(256) void transpose512_kernel(const float* __restrict__ in,
                                                           float* __restrict__ outT) {
  __shared__ float tile[32][33];
  int bx = blockIdx.x * 32, by = blockIdx.y * 32;
  int tx = threadIdx.x & 31, ty = threadIdx.x >> 5;   // 32x8
  #pragma unroll
  for (int yy = ty; yy < 32; yy += 8)
    tile[yy][tx] = in[(by + yy)*LL + bx + tx];
  __syncthreads();
  #pragma unroll
  for (int yy = ty; yy < 32; yy += 8)
    outT[(bx + yy)*LL + by + tx] = tile[tx][yy];
}

// ---------------- q/k/v projection + l2norm (4-way co-split) ----------------
// grid (144, 4); blockIdx.y = co-quarter (2 heads). qo fp32 [bt][l][32] scaled by
// 0.5*log2e; kbo bf16 [bt][l][32]; vbo fp32 [bt][l][32].
__global__ __launch_bounds__(256) void proj_kernel(
    const float* __restrict__ x,
    const float* __restrict__ Wq, const float* __restrict__ bq,
    const float* __restrict__ Wk, const float* __restrict__ bk,
    const float* __restrict__ Wv, const float* __restrict__ bv,
    float* __restrict__ qo, short* __restrict__ kbo, float* __restrict__ vbo) {
  int gidx = blockIdx.x * 256 + threadIdx.x;    // 0..36863
  int l  = gidx & (LL-1);
  int bt = gidx >> 9;
  int b = bt / TT, t = bt - b*TT;
  const int hq = blockIdx.y * 2;                // first head of this quarter

  float xv[CC];
  #pragma unroll
  for (int c = 0; c < CC; ++c)
    xv[c] = x[((b*CC + c)*TT + t)*LL + l];

  // Q (scaled)
  #pragma unroll
  for (int h = hq; h < hq + 2; ++h) {
    float yv[DD];
    #pragma unroll
    for (int d = 0; d < DD; ++d) {
      int co = h*DD + d;
      float acc = bq[co];
      #pragma unroll
      for (int ci = 0; ci < CC; ++ci) acc += xv[ci] * Wq[co*CC + ci];
      yv[d] = acc;
    }
    float n = sqrtf(yv[0]*yv[0] + yv[1]*yv[1] + yv[2]*yv[2] + yv[3]*yv[3]);
    float inv = 0.5f * RLN2 / fmaxf(n, 1e-12f);
    *reinterpret_cast<float4*>(&qo[((size_t)bt*LL + l)*CC + h*DD]) =
        make_float4(yv[0]*inv, yv[1]*inv, yv[2]*inv, yv[3]*inv);
  }
  // K -> bf16 (2 heads = 16B)
  {
    unsigned ku[4];
    #pragma unroll
    for (int hh = 0; hh < 2; ++hh) {
      int h = hq + hh;
      float yv[DD];
      #pragma unroll
      for (int d = 0; d < DD; ++d) {
        int co = h*DD + d;
        float acc = bk[co];
        #pragma unroll
        for (int ci = 0; ci < CC; ++ci) acc += xv[ci] * Wk[co*CC + ci];
        yv[d] = acc;
      }
      float n = sqrtf(yv[0]*yv[0] + yv[1]*yv[1] + yv[2]*yv[2] + yv[3]*yv[3]);
      float inv = 1.0f / fmaxf(n, 1e-12f);
      ku[hh*2]   = cvtpk(yv[0]*inv, yv[1]*inv);
      ku[hh*2+1] = cvtpk(yv[2]*inv, yv[3]*inv);
    }
    *reinterpret_cast<uint4*>(kbo + ((size_t)bt*LL + l)*CC + hq*DD) =
        make_uint4(ku[0], ku[1], ku[2], ku[3]);
  }
  // V fp32
  #pragma unroll
  for (int h = hq; h < hq + 2; ++h) {
    float yv[DD];
    #pragma unroll
    for (int d = 0; d < DD; ++d) {
      int co = h*DD + d;
      float acc = bv[co];
      #pragma unroll
      for (int ci = 0; ci < CC; ++ci) acc += xv[ci] * Wv[co*CC + ci];
      yv[d] = acc;
    }
    float n = sqrtf(yv[0]*yv[0] + yv[1]*yv[1] + yv[2]*yv[2] + yv[3]*yv[3]);
    float inv = 1.0f / fmaxf(n, 1e-12f);
    *reinterpret_cast<float4*>(&vbo[((size_t)bt*LL + l)*CC + h*DD]) =
        make_float4(yv[0]*inv, yv[1]*inv, yv[2]*inv, yv[3]*inv);
  }
}

// ---------------- Vt: VbT[bt][n=32][j=512] bf16 = vbo[bt][j][n] transposed ----------------
__global__ __launch_bounds__(256) void vbt_kernel(const float* __restrict__ vbo,
                                                  short* __restrict__ vt) {
  int bt = blockIdx.x;
  int n  = threadIdx.x & 31;
  int jc = threadIdx.x >> 5;          // 0..7, chunk of 64 j
  const float* src = vbo + ((size_t)bt*LL)*CC + n;
  int j0 = jc*64;
  unsigned u[32];
  #pragma unroll
  for (int jj = 0; jj < 32; ++jj) {
    float a = src[(size_t)(j0 + 2*jj)*CC];
    float b = src[(size_t)(j0 + 2*jj + 1)*CC];
    u[jj] = cvtpk(a, b);
  }
  uint4* dst = reinterpret_cast<uint4*>(vt + ((size_t)bt*CC + n)*LL + j0);
  #pragma unroll
  for (int wq = 0; wq < 8; ++wq)
    dst[wq] = make_uint4(u[wq*4], u[wq*4+1], u[wq*4+2], u[wq*4+3]);
}

// ---------------- fused attention (v12: MFMA, jp-outer / heads-inner) ----------------
// 1152 blocks x 256 thr. Block = (bt, 32-row i-block). Wave w: i-tile = iblk*32+(w&1)*16,
// heads H = (w>>1)*4 .. +3. Per jp (32-j window): K/V frags loaded ONCE, then 4 heads
// processed with independent chains (2 QK mfma w/ bias C-op -> exp2 -> cvt_pk ->
// 8 ds_bpermute -> 2 PV mfma each). Epilogue per head: denom xor-reduce + bpermute
// redistribute, scale by Wc[H,H']/S. One barrier (H-half combine).
// Layout facts [m89]: C/D col=lane&15,row=(lane>>4)*4+r; A[m=lane&15][k=(lane>>4)*8+e];
// B[k=(lane>>4)*8+e][n=lane&15].
__global__ __launch_bounds__(256, 2) void attn_kernel(
    const float* __restrict__ q, const short* __restrict__ kb,
    const short* __restrict__ vt,
    const float* __restrict__ Wl, const float* __restrict__ Wc,
    const float* __restrict__ mbr, float* __restrict__ xatt) {
  __shared__ float xch[2][64][9];   // H-hi partials, padded (conflict-free)

  const int wgid = blockIdx.x;
  const int id   = (wgid & 7) * 144 + (wgid >> 3);   // 1152 % 8 == 0 -> bijective
  const int bt   = id >> 4;       // [0,72)
  const int iblk = id & 15;       // 32-row block

  const int tid  = threadIdx.x;
  const int w    = __builtin_amdgcn_readfirstlane(tid >> 6);
  const int lane = tid & 63;
  const int g    = lane >> 4;     // 0..3
  const int c16  = lane & 15;
  const int it   = iblk*32 + (w & 1)*16;   // wave's i-tile base
  const int Hb   = (w >> 1)*4;

  // build 4 QM b-frags: B[k=c][n=i] = Wl[h(c)][H] * q[i][c]
  s8v bq4[4];
  {
    float qp[8];
    const float* qr = q + ((size_t)bt*LL + it + c16)*CC + g*8;
    float4 qa = *reinterpret_cast<const float4*>(qr);
    float4 qb = *reinterpret_cast<const float4*>(qr + 4);
    qp[0]=qa.x; qp[1]=qa.y; qp[2]=qa.z; qp[3]=qa.w;
    qp[4]=qb.x; qp[5]=qb.y; qp[6]=qb.z; qp[7]=qb.w;
    const int h0 = g*2;
    #pragma unroll
    for (int hh = 0; hh < 4; ++hh) {
      const int H = Hb + hh;
      const float wla = Wl[h0*HH + H];
      const float wlb = Wl[(h0+1)*HH + H];
      i4v uq;
      uq[0] = (int)cvtpk(qp[0]*wla, qp[1]*wla);
      uq[1] = (int)cvtpk(qp[2]*wla, qp[3]*wla);
      uq[2] = (int)cvtpk(qp[4]*wlb, qp[5]*wlb);
      uq[3] = (int)cvtpk(qp[6]*wlb, qp[7]*wlb);
      bq4[hh] = __builtin_bit_cast(s8v, uq);
    }
  }

  const short* kbase = kb + ((size_t)bt*LL)*CC + (size_t)c16*CC + g*8;
  const short* vb0 = vt + ((size_t)bt*CC)*LL + (size_t)c16*LL + 8*g;
  const short* vb1 = vb0 + 16*LL;
  const float* mbase = mbr + Hb*1024 + 511 + 4*g - it - c16;

  f4v t0[4], t1[4];
  float den[4];
  #pragma unroll
  for (int hh = 0; hh < 4; ++hh) {
    t0[hh] = (f4v){0.f,0.f,0.f,0.f};
    t1[hh] = (f4v){0.f,0.f,0.f,0.f};
    den[hh] = 0.f;
  }

  const int s0b = (c16 + 32*(g & 1))*4;    // bpermute byte addrs
  const int s1b = s0b + 64;
  const bool useA = (g < 2);

  #pragma unroll 1
  for (int jp = 0; jp < 16; ++jp) {
    const int j0 = jp*32;
    // K/V fragments: loaded once, shared by all 4 heads
    s8v ak0 = *reinterpret_cast<const s8v*>(kbase + (size_t)j0*CC);
    s8v ak1 = *reinterpret_cast<const s8v*>(kbase + (size_t)(j0+16)*CC);
    s8v v0  = *reinterpret_cast<const s8v*>(vb0 + j0);
    s8v v1  = *reinterpret_cast<const s8v*>(vb1 + j0);

    #pragma unroll
    for (int hh = 0; hh < 4; ++hh) {
      const float* m = mbase + hh*1024 + j0;
      unsigned uA0, uA1, uB0, uB1;
      {
        f4v cb = { m[0], m[1], m[2], m[3] };
        f4v d = __builtin_amdgcn_mfma_f32_16x16x32_bf16(ak0, bq4[hh], cb, 0, 0, 0);
        float e0 = exp2f(d[0]), e1 = exp2f(d[1]), e2 = exp2f(d[2]), e3 = exp2f(d[3]);
        den[hh] += (e0 + e1) + (e2 + e3);
        uA0 = cvtpk(e0, e1); uA1 = cvtpk(e2, e3);
      }
      {
        f4v cb = { m[16], m[17], m[18], m[19] };
        f4v d = __builtin_amdgcn_mfma_f32_16x16x32_bf16(ak1, bq4[hh], cb, 0, 0, 0);
        float e0 = exp2f(d[0]), e1 = exp2f(d[1]), e2 = exp2f(d[2]), e3 = exp2f(d[3]);
        den[hh] += (e0 + e1) + (e2 + e3);
        uB0 = cvtpk(e0, e1); uB1 = cvtpk(e2, e3);
      }
      int a00 = __builtin_amdgcn_ds_bpermute(s0b, (int)uA0);
      int b00 = __builtin_amdgcn_ds_bpermute(s0b, (int)uB0);
      int a01 = __builtin_amdgcn_ds_bpermute(s0b, (int)uA1);
      int b01 = __builtin_amdgcn_ds_bpermute(s0b, (int)uB1);
      int a10 = __builtin_amdgcn_ds_bpermute(s1b, (int)uA0);
      int b10 = __builtin_amdgcn_ds_bpermute(s1b, (int)uB0);
      int a11 = __builtin_amdgcn_ds_bpermute(s1b, (int)uA1);
      int b11 = __builtin_amdgcn_ds_bpermute(s1b, (int)uB1);
      i4v pv;
      pv[0] = useA ? a00 : b00;
      pv[1] = useA ? a01 : b01;
      pv[2] = useA ? a10 : b10;
      pv[3] = useA ? a11 : b11;
      s8v pa = __builtin_bit_cast(s8v, pv);
      t0[hh] = __builtin_amdgcn_mfma_f32_16x16x32_bf16(pa, v0, t0[hh], 0, 0, 0);
      t1[hh] = __builtin_amdgcn_mfma_f32_16x16x32_bf16(pa, v1, t1[hh], 0, 0, 0);
    }
  }

  // epilogue: per head, reduce denominator and fold Wc/S scale
  f4v fin0 = {0.f,0.f,0.f,0.f}, fin1 = {0.f,0.f,0.f,0.f};
  #pragma unroll
  for (int hh = 0; hh < 4; ++hh) {
    const int H = Hb + hh;
    float dn = den[hh];
    dn += __shfl_xor(dn, 16);
    dn += __shfl_xor(dn, 32);
    float inv = __builtin_amdgcn_rcpf(dn);
    const float wclo = Wc[H*HH + (c16 >> 2)];
    const float wchi = Wc[H*HH + 4 + (c16 >> 2)];
    #pragma unroll
    for (int r = 0; r < 4; ++r) {
      float ir = __int_as_float(
          __builtin_amdgcn_ds_bpermute((4*g + r)*4, __float_as_int(inv)));
      fin0[r] += t0[hh][r] * (ir * wclo);
      fin1[r] += t1[hh][r] * (ir * wchi);
    }
  }

  // combine H-halves (waves 2,3 -> 0,1), then coalesced write
  if (w >= 2) {
    #pragma unroll
    for (int r = 0; r < 4; ++r) {
      xch[w-2][lane][r]     = fin0[r];
      xch[w-2][lane][4 + r] = fin1[r];
    }
  }
  __syncthreads();
  if (w < 2) {
    #pragma unroll
    for (int r = 0; r < 4; ++r) {
      float o0 = fin0[r] + xch[w][lane][r];
      float o1 = fin1[r] + xch[w][lane][4 + r];
      const int i = it + 4*g + r;
      xatt[((size_t)bt*LL + i)*CC + c16]      = o0;
      xatt[((size_t)bt*LL + i)*CC + 16 + c16] = o1;
    }
  }
}

// ---------------- Wm projection (4-way co-split); t<8 -> out, t==8 -> xm8 ----------------
__global__ __launch_bounds__(256) void wm_kernel(
    const float* __restrict__ xatt, const float* __restrict__ Wm, const float* __restrict__ bm,
    float* __restrict__ out, float* __restrict__ xm8) {
  int gl = blockIdx.x * 64 + threadIdx.x;   // 0..36863
  int qy = threadIdx.y;                     // 0..3
  int l  = gl & (LL-1);
  int bt = gl >> 9;
  int b = bt / TT, t = bt - b*TT;
  float xv[CC];
  #pragma unroll
  for (int c = 0; c < CC; c += 4) {
    float4 x4 = *reinterpret_cast<const float4*>(&xatt[(size_t)gl*CC + c]);
    xv[c] = x4.x; xv[c+1] = x4.y; xv[c+2] = x4.z; xv[c+3] = x4.w;
  }
  #pragma unroll
  for (int u = 0; u < 8; ++u) {
    int co = qy*8 + u;
    float acc = bm[co];
    #pragma unroll
    for (int ci = 0; ci < CC; ++ci) acc += xv[ci] * Wm[co*CC + ci];
    if (t < TT-1) out[((b*CC + co)*TT + t)*LL + l] = acc;
    else          xm8[(b*CC + co)*LL + l] = acc;
  }
}

// ---------------- fused conv+BN+ReLU+token-linear+subtract ----------------
// block = (b, co), 512 thr (one per l). conv over (ci, t) -> y[l] -> LDS ->
// p[l'] = sum_l y[l] plwT[l][l'] + plb; out[t=8] = xm8 - p.
__global__ __launch_bounds__(512) void convpl_kernel(
    const float* __restrict__ out_in, const float* __restrict__ pp,
    const float* __restrict__ cw, const float* __restrict__ cb,
    const float* __restrict__ bng, const float* __restrict__ bnb,
    const float* __restrict__ plwT, const float* __restrict__ plb,
    const float* __restrict__ xm8, float* __restrict__ out) {
  __shared__ float sy[LL];
  int bc = blockIdx.x;            // b*32 + co
  int b = bc >> 5, co = bc & 31;
  int l = threadIdx.x;
  float acc = cb[co];
  #pragma unroll
  for (int ci = 0; ci < CC; ++ci) {
    const float* base = out_in + ((b*CC + ci)*TT)*LL + l;
    const float* wv = cw + (co*CC + ci)*TT;
    #pragma unroll
    for (int t = 0; t < TT-1; ++t) acc += base[t*LL] * wv[t];
    acc += pp[ci*LL + l] * wv[TT-1];
  }
  float scale = bng[co] * 0.999995000037499687f;   // 1/sqrt(1+1e-5)
  sy[l] = fmaxf(acc * scale + bnb[co], 0.f);
  __syncthreads();
  float accp = plb[l];
  #pragma unroll 4
  for (int ll = 0; ll < LL; ++ll)
    accp += sy[ll] * plwT[ll*LL + l];
  out[((b*CC + co)*TT + (TT-1))*LL + l] = xm8[bc*LL + l] - accp;
}

extern "C" void kernel_launch(void* const* d_in, const int* in_sizes, int n_in,
                              void* d_out, int out_size, void* d_ws, size_t ws_size,
                              hipStream_t stream) {
  const float* x    = (const float*)d_in[0];
  const float* Wq   = (const float*)d_in[1];
  const float* bq   = (const float*)d_in[2];
  const float* Wk   = (const float*)d_in[3];
  const float* bk   = (const float*)d_in[4];
  const float* Wv   = (const float*)d_in[5];
  const float* bv   = (const float*)d_in[6];
  const float* Wm   = (const float*)d_in[7];
  const float* bm   = (const float*)d_in[8];
  const float* Wl   = (const float*)d_in[9];
  const float* Wc   = (const float*)d_in[10];
  const float* rpb  = (const float*)d_in[11];
  const float* pp   = (const float*)d_in[12];
  const float* cw   = (const float*)d_in[13];
  const float* cb   = (const float*)d_in[14];
  const float* bng  = (const float*)d_in[15];
  const float* bnb  = (const float*)d_in[16];
  const float* plw  = (const float*)d_in[17];
  const float* plb  = (const float*)d_in[18];
  float* out = (float*)d_out;

  float* ws = (float*)d_ws;
  const size_t NE = (size_t)NBT*LL*CC;         // 1179648
  float* q_ws   = ws;                          // NE fp32 [bt][l][32]
  float* vb_ws  = q_ws + NE;                   // NE fp32 [bt][l][32]
  short* kb_ws  = (short*)(vb_ws + NE);        // NE bf16 [bt][l][32]
  short* vt_ws  = kb_ws + NE;                  // NE bf16 [bt][32][512]
  float* xatt   = (float*)(vt_ws + NE);        // NE fp32
  float* xm8    = xatt + NE;                   // 131072
  float* plwT   = xm8 + (size_t)BB*CC*LL;      // 262144
  float* mbias  = plwT + (size_t)LL*LL;        // 8*1024

  mixed_bias_kernel<<<2, 512, 0, stream>>>(rpb, Wl, mbias);
  transpose512_kernel<<<dim3(16,16), 256, 0, stream>>>(plw, plwT);
  proj_kernel<<<dim3(144,4), 256, 0, stream>>>(x, Wq, bq, Wk, bk, Wv, bv,
                                               q_ws, kb_ws, vb_ws);
  vbt_kernel<<<NBT, 256, 0, stream>>>(vb_ws, vt_ws);
  attn_kernel<<<NBT*16, 256, 0, stream>>>(q_ws, kb_ws, vt_ws, Wl, Wc, mbias, xatt);
  wm_kernel<<<576, dim3(64,4), 0, stream>>>(xatt, Wm, bm, out, xm8);
  convpl_kernel<<<BB*CC, LL, 0, stream>>>(out, pp, cw, cb, bng, bnb,
                                          plwT, plb, xm8, out);
}

// Round 13
// 114.870 us; speedup vs baseline: 12.7087x; 1.2297x over previous
//
#include <hip/hip_runtime.h>
#include <math.h>

#define BB 8
#define CC 32
#define TT 9
#define LL 512
#define HH 8
#define DD 4
#define NBT (BB*TT)          // 72
#define RELN (2*LL-1)        // 1023
#define RLN2 1.4426950408889634f

typedef float  f4v __attribute__((ext_vector_type(4)));
typedef int    i4v __attribute__((ext_vector_type(4)));
typedef short  s8v __attribute__((ext_vector_type(8)));   // 8 bf16 = 4 VGPRs

#define EXP2(x) __builtin_amdgcn_exp2f(x)   // raw v_exp_f32 (exp2f -> OCML call = ~10 inst)

__device__ __forceinline__ unsigned cvtpk(float lo, float hi) {
  unsigned u;
  asm("v_cvt_pk_bf16_f32 %0, %1, %2" : "=v"(u) : "v"(lo), "v"(hi));
  return u;
}

// ---- mixed bias, reversed + log2e-prescaled: mbr[Ho][x] = log2e * sum_h rpb[h][1022-x] Wl[h][Ho]
__global__ void mixed_bias_kernel(const float* __restrict__ rpb,
                                  const float* __restrict__ Wl,
                                  float* __restrict__ mbr) {
  int x = blockIdx.x * blockDim.x + threadIdx.x;
  if (x >= RELN) return;
  int idx = 1022 - x;
  float r[HH];
  #pragma unroll
  for (int h = 0; h < HH; ++h) r[h] = rpb[h*RELN + idx];
  #pragma unroll
  for (int Ho = 0; Ho < HH; ++Ho) {
    float acc = 0.f;
    #pragma unroll
    for (int h = 0; h < HH; ++h) acc += r[h] * Wl[h*HH + Ho];
    mbr[Ho*1024 + x] = RLN2 * acc;
  }
}

// ---------------- transpose pl_w (512x512): outT[l][l'] = in[l'][l] ----------------
__global__ __launch_bounds__(256) void transpose512_kernel(const float* __restrict__ in,
                                                           float* __restrict__ outT) {
  __shared__ float tile[32][33];
  int bx = blockIdx.x * 32, by = blockIdx.y * 32;
  int tx = threadIdx.x & 31, ty = threadIdx.x >> 5;   // 32x8
  #pragma unroll
  for (int yy = ty; yy < 32; yy += 8)
    tile[yy][tx] = in[(by + yy)*LL + bx + tx];
  __syncthreads();
  #pragma unroll
  for (int yy = ty; yy < 32; yy += 8)
    outT[(bx + yy)*LL + by + tx] = tile[tx][yy];
}

// ---------------- q/k/v projection + l2norm (4-way co-split) ----------------
__global__ __launch_bounds__(256) void proj_kernel(
    const float* __restrict__ x,
    const float* __restrict__ Wq, const float* __restrict__ bq,
    const float* __restrict__ Wk, const float* __restrict__ bk,
    const float* __restrict__ Wv, const float* __restrict__ bv,
    float* __restrict__ qo, short* __restrict__ kbo, float* __restrict__ vbo) {
  int gidx = blockIdx.x * 256 + threadIdx.x;    // 0..36863
  int l  = gidx & (LL-1);
  int bt = gidx >> 9;
  int b = bt / TT, t = bt - b*TT;
  const int hq = blockIdx.y * 2;                // first head of this quarter

  float xv[CC];
  #pragma unroll
  for (int c = 0; c < CC; ++c)
    xv[c] = x[((b*CC + c)*TT + t)*LL + l];

  // Q (scaled by 0.5*log2e)
  #pragma unroll
  for (int h = hq; h < hq + 2; ++h) {
    float yv[DD];
    #pragma unroll
    for (int d = 0; d < DD; ++d) {
      int co = h*DD + d;
      float acc = bq[co];
      #pragma unroll
      for (int ci = 0; ci < CC; ++ci) acc += xv[ci] * Wq[co*CC + ci];
      yv[d] = acc;
    }
    float n = sqrtf(yv[0]*yv[0] + yv[1]*yv[1] + yv[2]*yv[2] + yv[3]*yv[3]);
    float inv = 0.5f * RLN2 / fmaxf(n, 1e-12f);
    *reinterpret_cast<float4*>(&qo[((size_t)bt*LL + l)*CC + h*DD]) =
        make_float4(yv[0]*inv, yv[1]*inv, yv[2]*inv, yv[3]*inv);
  }
  // K -> bf16
  {
    unsigned ku[4];
    #pragma unroll
    for (int hh = 0; hh < 2; ++hh) {
      int h = hq + hh;
      float yv[DD];
      #pragma unroll
      for (int d = 0; d < DD; ++d) {
        int co = h*DD + d;
        float acc = bk[co];
        #pragma unroll
        for (int ci = 0; ci < CC; ++ci) acc += xv[ci] * Wk[co*CC + ci];
        yv[d] = acc;
      }
      float n = sqrtf(yv[0]*yv[0] + yv[1]*yv[1] + yv[2]*yv[2] + yv[3]*yv[3]);
      float inv = 1.0f / fmaxf(n, 1e-12f);
      ku[hh*2]   = cvtpk(yv[0]*inv, yv[1]*inv);
      ku[hh*2+1] = cvtpk(yv[2]*inv, yv[3]*inv);
    }
    *reinterpret_cast<uint4*>(kbo + ((size_t)bt*LL + l)*CC + hq*DD) =
        make_uint4(ku[0], ku[1], ku[2], ku[3]);
  }
  // V fp32
  #pragma unroll
  for (int h = hq; h < hq + 2; ++h) {
    float yv[DD];
    #pragma unroll
    for (int d = 0; d < DD; ++d) {
      int co = h*DD + d;
      float acc = bv[co];
      #pragma unroll
      for (int ci = 0; ci < CC; ++ci) acc += xv[ci] * Wv[co*CC + ci];
      yv[d] = acc;
    }
    float n = sqrtf(yv[0]*yv[0] + yv[1]*yv[1] + yv[2]*yv[2] + yv[3]*yv[3]);
    float inv = 1.0f / fmaxf(n, 1e-12f);
    *reinterpret_cast<float4*>(&vbo[((size_t)bt*LL + l)*CC + h*DD]) =
        make_float4(yv[0]*inv, yv[1]*inv, yv[2]*inv, yv[3]*inv);
  }
}

// ---------------- Vt: VbT[bt][n=32][j=512] bf16 = vbo[bt][j][n]; grid (72,4) ----------------
__global__ __launch_bounds__(256) void vbt_kernel(const float* __restrict__ vbo,
                                                  short* __restrict__ vt) {
  int bt = blockIdx.x;
  int qq = blockIdx.y;                // j-quarter
  int n  = threadIdx.x & 31;
  int sub = threadIdx.x >> 5;         // 0..7
  int j0 = qq*128 + sub*16;
  const float* src = vbo + ((size_t)bt*LL)*CC + n;
  unsigned u[8];
  #pragma unroll
  for (int jj = 0; jj < 8; ++jj) {
    float a = src[(size_t)(j0 + 2*jj)*CC];
    float b = src[(size_t)(j0 + 2*jj + 1)*CC];
    u[jj] = cvtpk(a, b);
  }
  uint4* dst = reinterpret_cast<uint4*>(vt + ((size_t)bt*CC + n)*LL + j0);
  dst[0] = make_uint4(u[0], u[1], u[2], u[3]);
  dst[1] = make_uint4(u[4], u[5], u[6], u[7]);
}

// ---------------- fused attention + Wm (v13) ----------------
// 1152 blocks x 256 thr. Block = (bt, 32-row i-block). Wave w: i-tile = iblk*32+(w&1)*16,
// heads H = (w>>1)*4..+3. jp-outer/heads-inner main loop (v12, verified). exp2 via raw
// v_exp_f32. Epilogue: H-half combine -> x_att tile in LDS -> in-block Wm matvec ->
// write out (t<8) / xm8 (t==8) directly. sWm padded [32][33]: bank = (co+c)%32, conflict-free.
__global__ __launch_bounds__(256, 2) void attn_kernel(
    const float* __restrict__ q, const short* __restrict__ kb,
    const short* __restrict__ vt,
    const float* __restrict__ Wl, const float* __restrict__ Wc,
    const float* __restrict__ mbr,
    const float* __restrict__ Wm, const float* __restrict__ bm,
    float* __restrict__ out, float* __restrict__ xm8) {
  __shared__ float xch[2][64][9];   // H-hi partials, padded
  __shared__ float xt[32][33];      // x_att tile, padded
  __shared__ float sWm[32][33];     // Wm[co][ci], padded
  __shared__ float sbm[32];

  const int wgid = blockIdx.x;
  const int id   = (wgid & 7) * 144 + (wgid >> 3);   // 1152 % 8 == 0 -> bijective
  const int bt   = id >> 4;       // [0,72)
  const int iblk = id & 15;       // 32-row block
  const int b    = bt / TT, t = bt - b*TT;

  const int tid  = threadIdx.x;
  const int w    = __builtin_amdgcn_readfirstlane(tid >> 6);
  const int lane = tid & 63;
  const int g    = lane >> 4;     // 0..3
  const int c16  = lane & 15;
  const int it   = iblk*32 + (w & 1)*16;   // wave's i-tile base
  const int Hb   = (w >> 1)*4;

  // preload Wm/bm -> LDS (visible after first barrier)
  {
    int c4 = tid * 4;               // 0..1023
    int co = c4 >> 5, ci = c4 & 31;
    float4 wv = *reinterpret_cast<const float4*>(Wm + co*CC + ci);
    sWm[co][ci] = wv.x; sWm[co][ci+1] = wv.y; sWm[co][ci+2] = wv.z; sWm[co][ci+3] = wv.w;
    if (tid < 32) sbm[tid] = bm[tid];
  }

  // build 4 QM b-frags: B[k=c][n=i] = Wl[h(c)][H] * q[i][c]
  s8v bq4[4];
  {
    float qp[8];
    const float* qr = q + ((size_t)bt*LL + it + c16)*CC + g*8;
    float4 qa = *reinterpret_cast<const float4*>(qr);
    float4 qb = *reinterpret_cast<const float4*>(qr + 4);
    qp[0]=qa.x; qp[1]=qa.y; qp[2]=qa.z; qp[3]=qa.w;
    qp[4]=qb.x; qp[5]=qb.y; qp[6]=qb.z; qp[7]=qb.w;
    const int h0 = g*2;
    #pragma unroll
    for (int hh = 0; hh < 4; ++hh) {
      const int H = Hb + hh;
      const float wla = Wl[h0*HH + H];
      const float wlb = Wl[(h0+1)*HH + H];
      i4v uq;
      uq[0] = (int)cvtpk(qp[0]*wla, qp[1]*wla);
      uq[1] = (int)cvtpk(qp[2]*wla, qp[3]*wla);
      uq[2] = (int)cvtpk(qp[4]*wlb, qp[5]*wlb);
      uq[3] = (int)cvtpk(qp[6]*wlb, qp[7]*wlb);
      bq4[hh] = __builtin_bit_cast(s8v, uq);
    }
  }

  const short* kbase = kb + ((size_t)bt*LL)*CC + (size_t)c16*CC + g*8;
  const short* vb0 = vt + ((size_t)bt*CC)*LL + (size_t)c16*LL + 8*g;
  const short* vb1 = vb0 + 16*LL;
  const float* mbase = mbr + Hb*1024 + 511 + 4*g - it - c16;

  f4v t0[4], t1[4];
  float den[4];
  #pragma unroll
  for (int hh = 0; hh < 4; ++hh) {
    t0[hh] = (f4v){0.f,0.f,0.f,0.f};
    t1[hh] = (f4v){0.f,0.f,0.f,0.f};
    den[hh] = 0.f;
  }

  const int s0b = (c16 + 32*(g & 1))*4;    // bpermute byte addrs
  const int s1b = s0b + 64;
  const bool useA = (g < 2);

  #pragma unroll 1
  for (int jp = 0; jp < 16; ++jp) {
    const int j0 = jp*32;
    s8v ak0 = *reinterpret_cast<const s8v*>(kbase + (size_t)j0*CC);
    s8v ak1 = *reinterpret_cast<const s8v*>(kbase + (size_t)(j0+16)*CC);
    s8v v0  = *reinterpret_cast<const s8v*>(vb0 + j0);
    s8v v1  = *reinterpret_cast<const s8v*>(vb1 + j0);

    #pragma unroll
    for (int hh = 0; hh < 4; ++hh) {
      const float* m = mbase + hh*1024 + j0;
      unsigned uA0, uA1, uB0, uB1;
      {
        f4v cb = { m[0], m[1], m[2], m[3] };
        f4v d = __builtin_amdgcn_mfma_f32_16x16x32_bf16(ak0, bq4[hh], cb, 0, 0, 0);
        float e0 = EXP2(d[0]), e1 = EXP2(d[1]), e2 = EXP2(d[2]), e3 = EXP2(d[3]);
        den[hh] += (e0 + e1) + (e2 + e3);
        uA0 = cvtpk(e0, e1); uA1 = cvtpk(e2, e3);
      }
      {
        f4v cb = { m[16], m[17], m[18], m[19] };
        f4v d = __builtin_amdgcn_mfma_f32_16x16x32_bf16(ak1, bq4[hh], cb, 0, 0, 0);
        float e0 = EXP2(d[0]), e1 = EXP2(d[1]), e2 = EXP2(d[2]), e3 = EXP2(d[3]);
        den[hh] += (e0 + e1) + (e2 + e3);
        uB0 = cvtpk(e0, e1); uB1 = cvtpk(e2, e3);
      }
      int a00 = __builtin_amdgcn_ds_bpermute(s0b, (int)uA0);
      int b00 = __builtin_amdgcn_ds_bpermute(s0b, (int)uB0);
      int a01 = __builtin_amdgcn_ds_bpermute(s0b, (int)uA1);
      int b01 = __builtin_amdgcn_ds_bpermute(s0b, (int)uB1);
      int a10 = __builtin_amdgcn_ds_bpermute(s1b, (int)uA0);
      int b10 = __builtin_amdgcn_ds_bpermute(s1b, (int)uB0);
      int a11 = __builtin_amdgcn_ds_bpermute(s1b, (int)uA1);
      int b11 = __builtin_amdgcn_ds_bpermute(s1b, (int)uB1);
      i4v pv;
      pv[0] = useA ? a00 : b00;
      pv[1] = useA ? a01 : b01;
      pv[2] = useA ? a10 : b10;
      pv[3] = useA ? a11 : b11;
      s8v pa = __builtin_bit_cast(s8v, pv);
      t0[hh] = __builtin_amdgcn_mfma_f32_16x16x32_bf16(pa, v0, t0[hh], 0, 0, 0);
      t1[hh] = __builtin_amdgcn_mfma_f32_16x16x32_bf16(pa, v1, t1[hh], 0, 0, 0);
    }
  }

  // epilogue: per head, reduce denominator and fold Wc/S scale
  f4v fin0 = {0.f,0.f,0.f,0.f}, fin1 = {0.f,0.f,0.f,0.f};
  #pragma unroll
  for (int hh = 0; hh < 4; ++hh) {
    const int H = Hb + hh;
    float dn = den[hh];
    dn += __shfl_xor(dn, 16);
    dn += __shfl_xor(dn, 32);
    float inv = __builtin_amdgcn_rcpf(dn);
    const float wclo = Wc[H*HH + (c16 >> 2)];
    const float wchi = Wc[H*HH + 4 + (c16 >> 2)];
    #pragma unroll
    for (int r = 0; r < 4; ++r) {
      float ir = __int_as_float(
          __builtin_amdgcn_ds_bpermute((4*g + r)*4, __float_as_int(inv)));
      fin0[r] += t0[hh][r] * (ir * wclo);
      fin1[r] += t1[hh][r] * (ir * wchi);
    }
  }

  // combine H-halves (waves 2,3 -> 0,1)
  if (w >= 2) {
    #pragma unroll
    for (int r = 0; r < 4; ++r) {
      xch[w-2][lane][r]     = fin0[r];
      xch[w-2][lane][4 + r] = fin1[r];
    }
  }
  __syncthreads();
  if (w < 2) {
    #pragma unroll
    for (int r = 0; r < 4; ++r) {
      float o0 = fin0[r] + xch[w][lane][r];
      float o1 = fin1[r] + xch[w][lane][4 + r];
      const int row = w*16 + 4*g + r;    // w<2: w == (w&1)
      xt[row][c16]      = o0;
      xt[row][16 + c16] = o1;
    }
  }
  __syncthreads();

  // in-block Wm: 1024 outputs over 256 threads (4 co each, one row)
  {
    const int row = tid & 31;
    const int cos = (tid >> 5) * 4;
    float a0 = sbm[cos], a1 = sbm[cos+1], a2 = sbm[cos+2], a3 = sbm[cos+3];
    #pragma unroll
    for (int c = 0; c < CC; ++c) {
      float xv = xt[row][c];
      a0 += xv * sWm[cos][c];
      a1 += xv * sWm[cos+1][c];
      a2 += xv * sWm[cos+2][c];
      a3 += xv * sWm[cos+3][c];
    }
    const int l = iblk*32 + row;
    float av[4] = {a0, a1, a2, a3};
    #pragma unroll
    for (int u = 0; u < 4; ++u) {
      int co = cos + u;
      if (t < TT-1) out[((b*CC + co)*TT + t)*LL + l] = av[u];
      else          xm8[(b*CC + co)*LL + l] = av[u];
    }
  }
}

// ---------------- fused conv+BN+ReLU+token-linear+subtract (1024 thr, 2-way split) --------
__global__ __launch_bounds__(1024) void convpl_kernel(
    const float* __restrict__ out_in, const float* __restrict__ pp,
    const float* __restrict__ cw, const float* __restrict__ cb,
    const float* __restrict__ bng, const float* __restrict__ bnb,
    const float* __restrict__ plwT, const float* __restrict__ plb,
    const float* __restrict__ xm8, float* __restrict__ out) {
  __shared__ float sy[LL];
  __shared__ float part[2][LL];
  int bc = blockIdx.x;            // b*32 + co
  int b = bc >> 5, co = bc & 31;
  int tid = threadIdx.x;
  int l = tid & (LL-1);
  int h = tid >> 9;               // 0,1

  float acc = (h == 0) ? cb[co] : 0.f;
  #pragma unroll
  for (int cc = 0; cc < 16; ++cc) {
    int ci = h*16 + cc;
    const float* base = out_in + ((b*CC + ci)*TT)*LL + l;
    const float* wv = cw + (co*CC + ci)*TT;
    #pragma unroll
    for (int tq = 0; tq < TT-1; ++tq) acc += base[tq*LL] * wv[tq];
    acc += pp[ci*LL + l] * wv[TT-1];
  }
  part[h][l] = acc;
  __syncthreads();
  if (h == 0) {
    float scale = bng[co] * 0.999995000037499687f;   // 1/sqrt(1+1e-5)
    sy[l] = fmaxf((part[0][l] + part[1][l]) * scale + bnb[co], 0.f);
  }
  __syncthreads();
  float accp = (h == 0) ? plb[l] : 0.f;
  #pragma unroll 4
  for (int lq = 0; lq < 256; ++lq) {
    int ll = h*256 + lq;
    accp += sy[ll] * plwT[ll*LL + l];
  }
  part[h][l] = accp;
  __syncthreads();
  if (h == 0)
    out[((b*CC + co)*TT + (TT-1))*LL + l] = xm8[bc*LL + l] - (part[0][l] + part[1][l]);
}

extern "C" void kernel_launch(void* const* d_in, const int* in_sizes, int n_in,
                              void* d_out, int out_size, void* d_ws, size_t ws_size,
                              hipStream_t stream) {
  const float* x    = (const float*)d_in[0];
  const float* Wq   = (const float*)d_in[1];
  const float* bq   = (const float*)d_in[2];
  const float* Wk   = (const float*)d_in[3];
  const float* bk   = (const float*)d_in[4];
  const float* Wv   = (const float*)d_in[5];
  const float* bv   = (const float*)d_in[6];
  const float* Wm   = (const float*)d_in[7];
  const float* bm   = (const float*)d_in[8];
  const float* Wl   = (const float*)d_in[9];
  const float* Wc   = (const float*)d_in[10];
  const float* rpb  = (const float*)d_in[11];
  const float* pp   = (const float*)d_in[12];
  const float* cw   = (const float*)d_in[13];
  const float* cb   = (const float*)d_in[14];
  const float* bng  = (const float*)d_in[15];
  const float* bnb  = (const float*)d_in[16];
  const float* plw  = (const float*)d_in[17];
  const float* plb  = (const float*)d_in[18];
  float* out = (float*)d_out;

  float* ws = (float*)d_ws;
  const size_t NE = (size_t)NBT*LL*CC;         // 1179648
  float* q_ws   = ws;                          // NE fp32 [bt][l][32]
  float* vb_ws  = q_ws + NE;                   // NE fp32 [bt][l][32]
  short* kb_ws  = (short*)(vb_ws + NE);        // NE bf16 [bt][l][32]
  short* vt_ws  = kb_ws + NE;                  // NE bf16 [bt][32][512]
  float* xm8    = (float*)(vt_ws + NE);        // 131072
  float* plwT   = xm8 + (size_t)BB*CC*LL;      // 262144
  float* mbias  = plwT + (size_t)LL*LL;        // 8*1024

  mixed_bias_kernel<<<2, 512, 0, stream>>>(rpb, Wl, mbias);
  transpose512_kernel<<<dim3(16,16), 256, 0, stream>>>(plw, plwT);
  proj_kernel<<<dim3(144,4), 256, 0, stream>>>(x, Wq, bq, Wk, bk, Wv, bv,
                                               q_ws, kb_ws, vb_ws);
  vbt_kernel<<<dim3(NBT,4), 256, 0, stream>>>(vb_ws, vt_ws);
  attn_kernel<<<NBT*16, 256, 0, stream>>>(q_ws, kb_ws, vt_ws, Wl, Wc, mbias,
                                          Wm, bm, out, xm8);
  convpl_kernel<<<BB*CC, 1024, 0, stream>>>(out, pp, cw, cb, bng, bnb,
                                            plwT, plb, xm8, out);
}